// Round 14
// baseline (320.450 us; speedup 1.0000x reference)
//
#include <hip/hip_runtime.h>
#include <hip/hip_bf16.h>
#include <math.h>

// ---------------------------------------------------------------------------
// GAT: 2x GATConv(heads=1) + global mean pool + FC(64->2)
// R25 = R24 (318.8 ~= best 317.5) + NPB 256->128 for the CSR build.
//   R24 post-mortem: int4 partition loads neutral -> load-issue levers
//   exhausted. Budget reconstruction: build_csr ~25us is the worst-
//   parallelized kernel (391 blocks = 1.5/CU, ~50 barriers + 3 passes over
//   ~4092 edges serially per block). NPB=128: 782 blocks (3/CU), half the
//   per-block serial work -> csr dur ~halves. Partition packs d>>7/d&127
//   (R15-validated at NB=782), PSTRIDE 2368 (lambda=2046,+7sigma).
//   bufH16 now explicitly 16B-aligned (old layout was aligned by luck).
//   Aggregate / gemm / pool_fc BYTE-IDENTICAL (R19/R20 knife-edge lesson).
// ---------------------------------------------------------------------------

#define NPB 128          // nodes per bucket
#define EPB 4096         // edges per partition block (256 thr x 16)
#define PSTRIDE 2368     // slots per bucket (lambda=2046, +7 sigma)
#define XPAD 68          // xs leading-dim pad: 8-way banks, 16B-aligned rows

__device__ __forceinline__ unsigned int f2bf(float v) {
    unsigned int b = __float_as_uint(v);
    b += 0x7FFFu + ((b >> 16) & 1u);   // round-to-nearest-even
    return b >> 16;
}

// --- init: zero bucket cursors ----------------------------------------------
__global__ __launch_bounds__(256) void init_all(int* __restrict__ bcur, int NB) {
    int i = blockIdx.x * 256 + threadIdx.x;
    if (i < NB) bcur[i] = 0;
}

// --- partition edges into fixed-stride dst-buckets (packed uint32) ----------
// int4 loads (4 edges per vector); bk = d>>7, low7 bits of d in top byte.
__global__ __launch_bounds__(256) void partition(const int* __restrict__ ei,
                                                 int E, int NB,
                                                 int* __restrict__ bcur,
                                                 unsigned int* __restrict__ pairs) {
    __shared__ int h[1024];
    __shared__ int hb[1024];
    int t = threadIdx.x;
    for (int i = t; i < 1024; i += 256) h[i] = 0;
    __syncthreads();
    int i0 = blockIdx.x * EPB;
    unsigned int val[16];
    int bk[16], r[16];
    const int4* s4p = (const int4*)(ei);
    const int4* d4p = (const int4*)(ei + E);
#pragma unroll
    for (int k = 0; k < 4; k++) {
        int vbase = (i0 >> 2) + k * 256 + t;   // int4 index
        int i = vbase << 2;                    // first edge of this chunk
        if (i < E) {                           // E%4==0 -> whole int4 valid
            int4 s4 = s4p[vbase];
            int4 d4 = d4p[vbase];
            int ss[4] = {s4.x, s4.y, s4.z, s4.w};
            int dd[4] = {d4.x, d4.y, d4.z, d4.w};
#pragma unroll
            for (int j = 0; j < 4; j++) {
                int e = k * 4 + j;
                bk[e] = dd[j] >> 7;
                val[e] = (unsigned)ss[j] | ((unsigned)(dd[j] & 127) << 24);
                r[e] = atomicAdd(&h[bk[e]], 1);
            }
        } else {
#pragma unroll
            for (int j = 0; j < 4; j++) bk[k * 4 + j] = -1;
        }
    }
    __syncthreads();
    for (int b = t; b < NB; b += 256)
        hb[b] = h[b] ? atomicAdd(&bcur[b], h[b]) : 0;
    __syncthreads();
#pragma unroll
    for (int e = 0; e < 16; e++) {
        if (bk[e] < 0) continue;
        int pos = hb[bk[e]] + r[e];
        if (pos < PSTRIDE)                 // overflow guard (stat. impossible)
            pairs[(size_t)bk[e] * PSTRIDE + pos] = val[e];
    }
}

// --- per-bucket CSR fill with FUSED counting sort by src>>9 -----------------
// Sort in LDS (Q), then degree/scan/fill directly from Q. Each node's CSR
// list fills ~ascending in src (convoy). NPB=128: 782 blocks, half the
// per-block serial chain of the NPB=256 version.
__global__ __launch_bounds__(256) void build_csr(const unsigned int* __restrict__ pairs,
                                                 const int* __restrict__ bcur,
                                                 int n, int NB,
                                                 int* __restrict__ rowptr,
                                                 int* __restrict__ srcs) {
    int b = blockIdx.x, t = threadIdx.x;
    __shared__ int c[1024];
    __shared__ int s2[256];
    __shared__ int sbase, stot;
    __shared__ unsigned int Q[PSTRIDE];   // 9.25 KB sorted bucket
    __shared__ int hist[256];
    __shared__ int hcur[256];
    // ---- global bucket-count scan, 4 counts/thread (NB <= 1024) ----
    int sum4 = 0;
#pragma unroll
    for (int q = 0; q < 4; q++) {
        int bi = 4 * t + q;
        int cv = (bi < NB) ? min(bcur[bi], PSTRIDE) : 0;
        c[bi] = cv;
        sum4 += cv;
    }
    s2[t] = sum4;
    hist[t] = 0;
    __syncthreads();
    for (int o = 1; o < 256; o <<= 1) {
        int u = (t >= o) ? s2[t - o] : 0;
        __syncthreads();
        s2[t] += u;
        __syncthreads();
    }
    if (t == 0) {
        int p = b >> 2;
        int gsum = c[4 * p] + c[4 * p + 1] + c[4 * p + 2] + c[4 * p + 3];
        int ex = s2[p] - gsum;               // pairs in groups before p
        for (int q = 0; q < (b & 3); q++) ex += c[4 * p + q];
        sbase = ex;                          // pairs in buckets before b
        stot = s2[255];
    }
    __syncthreads();
    int d0 = b << 7;
    int nb = min(NPB, n - d0);
    int cnt_b = c[b];
    int csr0 = sbase + d0;   // pairs before + one self-loop per node before
    const unsigned int* pb = pairs + (size_t)b * PSTRIDE;

    // ---- counting sort by src>>9 into Q ----
    for (int j = t; j < cnt_b; j += 256)
        atomicAdd(&hist[(pb[j] & 0xFFFFFFu) >> 9], 1);   // key <= 195
    __syncthreads();
    int hv = hist[t];
    hcur[t] = hv;
    __syncthreads();
    for (int o = 1; o < 256; o <<= 1) {
        int u = (t >= o) ? hcur[t - o] : 0;
        __syncthreads();
        hcur[t] += u;
        __syncthreads();
    }
    hcur[t] -= hv;                        // exclusive base -> cursor
    __syncthreads();
    for (int j = t; j < cnt_b; j += 256) {
        unsigned int p = pb[j];
        int pos = atomicAdd(&hcur[(p & 0xFFFFFFu) >> 9], 1);
        Q[pos] = p;
    }
    __syncthreads();

    // ---- degree count / scan / fill from sorted Q (arrays = 128) ----
    __shared__ int deg[NPB];
    __shared__ int cur[NPB];
    __shared__ int tmp[NPB];
    if (t < NPB) deg[t] = (t < nb) ? 1 : 0;   // self-loop
    __syncthreads();
    for (int j = t; j < cnt_b; j += 256)
        atomicAdd(&deg[Q[j] >> 24], 1);
    __syncthreads();
    int v = (t < NPB) ? deg[t] : 0;
    if (t < NPB) tmp[t] = v;
    __syncthreads();
    for (int o = 1; o < NPB; o <<= 1) {
        int u = (t >= o && t < NPB) ? tmp[t - o] : 0;
        __syncthreads();
        if (t < NPB) tmp[t] += u;
        __syncthreads();
    }
    int excl = (t < NPB) ? (tmp[t] - v) : 0;
    if (t < nb) {
        rowptr[d0 + t] = csr0 + excl;
        srcs[csr0 + excl] = d0 + t;   // self-loop at slot 0
        cur[t] = excl + 1;
    }
    __syncthreads();
    // j-round order over sorted Q -> each node's list fills ~ascending in src
    for (int j = t; j < cnt_b; j += 256) {
        unsigned int p = Q[j];
        int off = atomicAdd(&cur[p >> 24], 1);
        srcs[csr0 + off] = (int)(p & 0x00FFFFFFu);
    }
    if (b == 0 && t == 0) rowptr[n] = n + stot;
}

// --- tiled node GEMM: 64 nodes x 64 cols per block, 4x4 per thread ----------
// float4-vectorized x staging (R21; a float4 never straddles lim since
// IN_DIM % 4 == 0 and lim is a multiple of IN_DIM).
template <int IN_DIM>
__global__ __launch_bounds__(256) void node_gemm(const float* __restrict__ x,
                                                 const float* __restrict__ W,
                                                 const float* __restrict__ a_src,
                                                 const float* __restrict__ a_dst,
                                                 const float* __restrict__ bias_in,
                                                 float slope_in,
                                                 unsigned short* __restrict__ h16,
                                                 float* __restrict__ al_s,
                                                 float* __restrict__ al_d,
                                                 int n) {
    __shared__ float Ws[IN_DIM * 64];
    __shared__ float xs[IN_DIM][XPAD];
    int t = threadIdx.x;
    int nbase = blockIdx.x * 64;

    for (int idx = t; idx < IN_DIM * 16; idx += 256)
        ((float4*)Ws)[idx] = ((const float4*)W)[idx];
    const float* xb = x + (size_t)nbase * IN_DIM;
    int lim = min(64, n - nbase) * IN_DIM;           // in floats
    constexpr int NV = (64 * IN_DIM) / 4;            // float4 elements
    for (int idx = t; idx < NV; idx += 256) {
        int f0 = idx * 4;
        float4 v = make_float4(0.0f, 0.0f, 0.0f, 0.0f);
        if (f0 < lim) v = ((const float4*)xb)[idx];  // coalesced 16B/lane
        int node = f0 / IN_DIM;
        int k = f0 - node * IN_DIM;
        if (bias_in) {
            v.x += bias_in[k + 0];
            v.y += bias_in[k + 1];
            v.z += bias_in[k + 2];
            v.w += bias_in[k + 3];
            v.x = (v.x >= 0.0f) ? v.x : slope_in * v.x;
            v.y = (v.y >= 0.0f) ? v.y : slope_in * v.y;
            v.z = (v.z >= 0.0f) ? v.z : slope_in * v.z;
            v.w = (v.w >= 0.0f) ? v.w : slope_in * v.w;
        }
        xs[k + 0][node] = v.x;
        xs[k + 1][node] = v.y;
        xs[k + 2][node] = v.z;
        xs[k + 3][node] = v.w;
    }
    __syncthreads();

    int cg = t & 15;    // col group: cols 4cg..4cg+3
    int ng = t >> 4;    // node group: nodes 4ng..4ng+3
    float acc[4][4] = {};
#pragma unroll 8
    for (int k = 0; k < IN_DIM; k++) {
        float4 xv = *(const float4*)&xs[k][ng * 4];
        float4 wv = *(const float4*)&Ws[k * 64 + cg * 4];
        float xa[4] = {xv.x, xv.y, xv.z, xv.w};
        float wa[4] = {wv.x, wv.y, wv.z, wv.w};
#pragma unroll
        for (int i = 0; i < 4; i++)
#pragma unroll
            for (int j = 0; j < 4; j++)
                acc[i][j] += xa[i] * wa[j];
    }

    float4 as4 = *(const float4*)(a_src + cg * 4);
    float4 ad4 = *(const float4*)(a_dst + cg * 4);
#pragma unroll
    for (int i = 0; i < 4; i++) {
        int node = nbase + ng * 4 + i;
        if (node < n) {
            uint2 p;
            p.x = f2bf(acc[i][0]) | (f2bf(acc[i][1]) << 16);
            p.y = f2bf(acc[i][2]) | (f2bf(acc[i][3]) << 16);
            *(uint2*)(h16 + (size_t)node * 64 + cg * 4) = p;
        }
        float vs = acc[i][0] * as4.x + acc[i][1] * as4.y +
                   acc[i][2] * as4.z + acc[i][3] * as4.w;
        float vd = acc[i][0] * ad4.x + acc[i][1] * ad4.y +
                   acc[i][2] * ad4.z + acc[i][3] * ad4.w;
#pragma unroll
        for (int o = 8; o; o >>= 1) {
            vs += __shfl_xor(vs, o);
            vd += __shfl_xor(vd, o);
        }
        if (cg == 0 && node < n) { al_s[node] = vs; al_d[node] = vd; }
    }
}

// --- single-pass aggregate (R17 proven body, BYTE-IDENTICAL): ---------------
// 8 lanes/node, depth-4 prefetch. 53.4us / 32 VGPR / no spill.
// out[node] = (sum_j exp(e_j)*h[src_j]) / (sum_j exp(e_j) + 1e-16)
__device__ __forceinline__ void bf8_fma(float* acc, uint4 q, float w) {
    acc[0] += w * __uint_as_float(q.x << 16);
    acc[1] += w * __uint_as_float(q.x & 0xFFFF0000u);
    acc[2] += w * __uint_as_float(q.y << 16);
    acc[3] += w * __uint_as_float(q.y & 0xFFFF0000u);
    acc[4] += w * __uint_as_float(q.z << 16);
    acc[5] += w * __uint_as_float(q.z & 0xFFFF0000u);
    acc[6] += w * __uint_as_float(q.w << 16);
    acc[7] += w * __uint_as_float(q.w & 0xFFFF0000u);
}

__global__ __launch_bounds__(256) void gat_aggregate(const int* __restrict__ rowptr,
                                                     const int* __restrict__ srcs,
                                                     const float* __restrict__ als,
                                                     const float* __restrict__ ald,
                                                     const unsigned short* __restrict__ h16,
                                                     float* __restrict__ hout,
                                                     int n) {
    int t = threadIdx.x;
    int sub = t >> 3, lane = t & 7;       // 32 nodes/block, 8 lanes/node
    int node = blockIdx.x * 32 + sub;
    if (node >= n) return;
    int beg = rowptr[node], end = rowptr[node + 1];
    float aldv = ald[node];
    const unsigned short* hb = h16 + lane * 8;

    float acc[8] = {};
    float sm = 0.0f;
    int j = beg;
    if (j + 4 <= end) {
        int s0 = srcs[j], s1 = srcs[j + 1], s2 = srcs[j + 2], s3 = srcs[j + 3];
        for (; j + 8 <= end; j += 4) {
            // prefetch next quad's indices: breaks srcs->gather serial chain
            int n0 = srcs[j + 4], n1 = srcs[j + 5];
            int n2 = srcs[j + 6], n3 = srcs[j + 7];
            float e0 = als[s0] + aldv, e1 = als[s1] + aldv;
            float e2 = als[s2] + aldv, e3 = als[s3] + aldv;
            uint4 q0 = *(const uint4*)(hb + (size_t)s0 * 64);
            uint4 q1 = *(const uint4*)(hb + (size_t)s1 * 64);
            uint4 q2 = *(const uint4*)(hb + (size_t)s2 * 64);
            uint4 q3 = *(const uint4*)(hb + (size_t)s3 * 64);
            e0 = (e0 >= 0.0f) ? e0 : 0.2f * e0;
            e1 = (e1 >= 0.0f) ? e1 : 0.2f * e1;
            e2 = (e2 >= 0.0f) ? e2 : 0.2f * e2;
            e3 = (e3 >= 0.0f) ? e3 : 0.2f * e3;
            float w0 = __expf(e0), w1 = __expf(e1);
            float w2 = __expf(e2), w3 = __expf(e3);
            sm += (w0 + w1) + (w2 + w3);
            bf8_fma(acc, q0, w0);
            bf8_fma(acc, q1, w1);
            bf8_fma(acc, q2, w2);
            bf8_fma(acc, q3, w3);
            s0 = n0; s1 = n1; s2 = n2; s3 = n3;
        }
        // final full quad (s0..s3 already loaded)
        {
            float e0 = als[s0] + aldv, e1 = als[s1] + aldv;
            float e2 = als[s2] + aldv, e3 = als[s3] + aldv;
            uint4 q0 = *(const uint4*)(hb + (size_t)s0 * 64);
            uint4 q1 = *(const uint4*)(hb + (size_t)s1 * 64);
            uint4 q2 = *(const uint4*)(hb + (size_t)s2 * 64);
            uint4 q3 = *(const uint4*)(hb + (size_t)s3 * 64);
            e0 = (e0 >= 0.0f) ? e0 : 0.2f * e0;
            e1 = (e1 >= 0.0f) ? e1 : 0.2f * e1;
            e2 = (e2 >= 0.0f) ? e2 : 0.2f * e2;
            e3 = (e3 >= 0.0f) ? e3 : 0.2f * e3;
            float w0 = __expf(e0), w1 = __expf(e1);
            float w2 = __expf(e2), w3 = __expf(e3);
            sm += (w0 + w1) + (w2 + w3);
            bf8_fma(acc, q0, w0);
            bf8_fma(acc, q1, w1);
            bf8_fma(acc, q2, w2);
            bf8_fma(acc, q3, w3);
            j += 4;
        }
    }
    for (; j < end; j++) {
        int s = srcs[j];
        float e = als[s] + aldv;
        e = (e >= 0.0f) ? e : 0.2f * e;
        float w = __expf(e);
        uint4 q = *(const uint4*)(hb + (size_t)s * 64);
        sm += w;
        bf8_fma(acc, q, w);
    }

    float inv = 1.0f / (sm + 1e-16f);
    float4 o0 = make_float4(acc[0] * inv, acc[1] * inv, acc[2] * inv, acc[3] * inv);
    float4 o1 = make_float4(acc[4] * inv, acc[5] * inv, acc[6] * inv, acc[7] * inv);
    float* op = hout + (size_t)node * 64 + lane * 8;
    *(float4*)op = o0;
    *(float4*)(op + 4) = o1;
}

// --- fused pool + FC: one block per graph, binary-search batch bounds -------
__global__ __launch_bounds__(256) void pool_fc(const float* __restrict__ hout,
                                               const float* __restrict__ b2,
                                               const int* __restrict__ batch,
                                               const float* __restrict__ fcW,
                                               const float* __restrict__ fcb,
                                               float* __restrict__ out, int n) {
    int g = blockIdx.x;
    int t = threadIdx.x;
    __shared__ int sLo, sHi;
    __shared__ float red[4][64];
    if (t == 0) {
        int lo = 0, hi = n;
        while (lo < hi) { int m = (lo + hi) >> 1; if (batch[m] < g) lo = m + 1; else hi = m; }
        sLo = lo;
    } else if (t == 64) {
        int lo = 0, hi = n;
        while (lo < hi) { int m = (lo + hi) >> 1; if (batch[m] < g + 1) lo = m + 1; else hi = m; }
        sHi = lo;
    }
    __syncthreads();
    int lo = sLo, hi = sHi;
    int wv = t >> 6, lane = t & 63;
    float acc = 0.0f;
    for (int node = lo + wv; node < hi; node += 4)
        acc += hout[(size_t)node * 64 + lane];
    red[wv][lane] = acc;
    __syncthreads();
    if (wv == 0) {
        float c = (float)(hi - lo);
        float s = red[0][lane] + red[1][lane] + red[2][lane] + red[3][lane];
        s += c * b2[lane];
        float cd = (c > 1.0f) ? c : 1.0f;
        float p = s / cd;
        float s0 = p * fcW[lane * 2 + 0];
        float s1 = p * fcW[lane * 2 + 1];
#pragma unroll
        for (int o = 32; o; o >>= 1) {
            s0 += __shfl_xor(s0, o);
            s1 += __shfl_xor(s1, o);
        }
        if (lane == 0) {
            out[g * 2 + 0] = s0 + fcb[0];
            out[g * 2 + 1] = s1 + fcb[1];
        }
    }
}

extern "C" void kernel_launch(void* const* d_in, const int* in_sizes, int n_in,
                              void* d_out, int out_size, void* d_ws, size_t ws_size,
                              hipStream_t stream) {
    const float* x    = (const float*)d_in[0];
    const int*   ei   = (const int*)d_in[1];
    const int*   batch= (const int*)d_in[2];
    const float* W1   = (const float*)d_in[3];
    const float* as1  = (const float*)d_in[4];
    const float* ad1  = (const float*)d_in[5];
    const float* b1   = (const float*)d_in[6];
    const float* W2   = (const float*)d_in[7];
    const float* as2  = (const float*)d_in[8];
    const float* ad2  = (const float*)d_in[9];
    const float* b2   = (const float*)d_in[10];
    const float* fcW  = (const float*)d_in[11];
    const float* fcb  = (const float*)d_in[12];
    float* out = (float*)d_out;

    const int N = in_sizes[2];       // 100000
    const int E = in_sizes[1] / 2;   // 1600000
    const int G = out_size / 2;      // 256
    const int tot = E + N;
    const int NB = (N + NPB - 1) / NPB;   // 782 buckets

    // ws layout (~46 MiB): pairs ALIASES bufO (disjoint lifetimes:
    // pairs die at build_csr; bufO first written by aggregate layer 1).
    float* ws     = (float*)d_ws;
    float* bufO   = ws;                                  // N*64 fp32  25.6 MB
    unsigned int* pairs  = (unsigned int*)bufO;          // alias      7.4 MB
    float* als    = bufO + (size_t)N * 64;               // N          0.4 MB
    float* ald    = als + N;                             // N          0.4 MB
    int*   rowptr = (int*)(ald + N);                     // N+1        0.4 MB
    int*   srcs   = rowptr + N + 1;                      // tot        6.8 MB
    int*   bcur   = srcs + tot;                          // NB
    unsigned short* bufH16 =                             // N*64 bf16 12.8 MB
        (unsigned short*)(((uintptr_t)(bcur + NB) + 15) & ~(uintptr_t)15);

    dim3 b256(256);
    int gInit = (NB + 255) / 256;
    int gPart = (E + EPB - 1) / EPB;
    int gGemm = (N + 63) / 64;
    int gAgg  = (N + 31) / 32;

    // ---- CSR build: partition + fused sort/fill -----------------------------
    init_all<<<gInit, b256, 0, stream>>>(bcur, NB);
    partition<<<gPart, b256, 0, stream>>>(ei, E, NB, bcur, pairs);
    build_csr<<<NB, b256, 0, stream>>>(pairs, bcur, N, NB, rowptr, srcs);

    // ---- layer 1 ----
    node_gemm<72><<<gGemm, b256, 0, stream>>>(x, W1, as1, ad1, nullptr, 0.0f,
                                              bufH16, als, ald, N);
    gat_aggregate<<<gAgg, b256, 0, stream>>>(rowptr, srcs, als, ald, bufH16, bufO, N);

    // ---- layer 2 (input = leaky(bufO + b1, 0.01)) ----
    node_gemm<64><<<gGemm, b256, 0, stream>>>(bufO, W2, as2, ad2, b1, 0.01f,
                                              bufH16, als, ald, N);
    gat_aggregate<<<gAgg, b256, 0, stream>>>(rowptr, srcs, als, ald, bufH16, bufO, N);

    // ---- fused pool + fc ----
    pool_fc<<<G, b256, 0, stream>>>(bufO, b2, batch, fcW, fcb, out, N);
}

// Round 15
// 310.648 us; speedup vs baseline: 1.0316x; 1.0316x over previous
//
#include <hip/hip_runtime.h>
#include <hip/hip_bf16.h>
#include <math.h>

// ---------------------------------------------------------------------------
// GAT: 2x GATConv(heads=1) + global mean pool + FC(64->2)
// R26 = R21 (best, 317.5us) + coalesced scatter in partition & build_csr.
//   Budget re-derivation (R24/R25 neutral forced it): non-agg 210us is
//   dominated by scattered 4B global writes -- partition's pairs scatter
//   (~100MB effective line traffic) and build_csr's srcs scatter. Fix:
//   stage both scatters in LDS, flush linearly (runs of ~10 / fully
//   contiguous) -> write amplification ~16x -> ~1.5x.
//   Aggregate (R17 body) / node_gemm (R21 float4) / pool_fc BYTE-IDENTICAL.
// ---------------------------------------------------------------------------

#define NPB 256          // nodes per bucket
#define EPB 4096         // edges per partition block (256 thr x 16)
#define PSTRIDE 4608     // slots per bucket (lambda=4092, +8 sigma)
#define XPAD 68          // xs leading-dim pad: 8-way banks, 16B-aligned rows

__device__ __forceinline__ unsigned int f2bf(float v) {
    unsigned int b = __float_as_uint(v);
    b += 0x7FFFu + ((b >> 16) & 1u);   // round-to-nearest-even
    return b >> 16;
}

// --- init: zero bucket cursors ----------------------------------------------
__global__ __launch_bounds__(256) void init_all(int* __restrict__ bcur, int NB) {
    int i = blockIdx.x * 256 + threadIdx.x;
    if (i < NB) bcur[i] = 0;
}

// --- partition edges into fixed-stride dst-buckets (packed uint32) ----------
// R26: LDS-staged coalesced flush. count -> scan -> LDS scatter (Qp,Bq by
// local rank) -> linear flush (consecutive j = same bucket = adjacent global
// positions). int4 edge loads (R24-validated).
__global__ __launch_bounds__(256) void partition(const int* __restrict__ ei,
                                                 int E, int NB,
                                                 int* __restrict__ bcur,
                                                 unsigned int* __restrict__ pairs) {
    __shared__ int h[512];                 // per-bucket counts
    __shared__ int ls[512];                // exclusive local starts
    __shared__ int lcur[512];              // scatter cursors
    __shared__ int hb[512];                // global bases
    __shared__ int s2[256];
    __shared__ unsigned int Qp[EPB];       // 16 KB staged vals
    __shared__ unsigned short Bq[EPB];     // 8 KB bucket ids
    int t = threadIdx.x;
    for (int i = t; i < 512; i += 256) h[i] = 0;
    __syncthreads();
    int i0 = blockIdx.x * EPB;
    unsigned int val[16];
    int bk[16];
    const int4* s4p = (const int4*)(ei);
    const int4* d4p = (const int4*)(ei + E);
#pragma unroll
    for (int k = 0; k < 4; k++) {
        int vbase = (i0 >> 2) + k * 256 + t;   // int4 index
        int i = vbase << 2;
        if (i < E) {                           // E%4==0 -> whole int4 valid
            int4 s4 = s4p[vbase];
            int4 d4 = d4p[vbase];
            int ss[4] = {s4.x, s4.y, s4.z, s4.w};
            int dd[4] = {d4.x, d4.y, d4.z, d4.w};
#pragma unroll
            for (int j = 0; j < 4; j++) {
                int e = k * 4 + j;
                bk[e] = dd[j] >> 8;
                val[e] = (unsigned)ss[j] | ((unsigned)(dd[j] & 255) << 24);
                atomicAdd(&h[bk[e]], 1);
            }
        } else {
#pragma unroll
            for (int j = 0; j < 4; j++) bk[k * 4 + j] = -1;
        }
    }
    __syncthreads();
    // exclusive scan of h[0..511] -> ls (pairwise, 256 threads)
    int p0 = h[2 * t], p1 = h[2 * t + 1];
    s2[t] = p0 + p1;
    __syncthreads();
    for (int o = 1; o < 256; o <<= 1) {
        int u = (t >= o) ? s2[t - o] : 0;
        __syncthreads();
        s2[t] += u;
        __syncthreads();
    }
    int ex = s2[t] - p0 - p1;
    ls[2 * t] = ex;           ls[2 * t + 1] = ex + p0;
    lcur[2 * t] = ex;         lcur[2 * t + 1] = ex + p0;
    __syncthreads();
    // global bases (one atomic per non-empty bucket)
    for (int b = t; b < NB; b += 256)
        hb[b] = h[b] ? atomicAdd(&bcur[b], h[b]) : 0;
    __syncthreads();
    // LDS scatter by local rank
#pragma unroll
    for (int e = 0; e < 16; e++) {
        if (bk[e] < 0) continue;
        int pos = atomicAdd(&lcur[bk[e]], 1);
        Qp[pos] = val[e];
        Bq[pos] = (unsigned short)bk[e];
    }
    __syncthreads();
    // linear flush: consecutive j -> same bucket -> adjacent global slots
    int total = s2[255];
    for (int j = t; j < total; j += 256) {
        int bkj = Bq[j];
        int gp = hb[bkj] + (j - ls[bkj]);
        if (gp < PSTRIDE)                  // overflow guard (stat. impossible)
            pairs[(size_t)bkj * PSTRIDE + gp] = Qp[j];
    }
}

// --- per-bucket CSR fill with FUSED counting sort by src>>9 -----------------
// R26: srcs segment built in LDS S[] then flushed linearly (coalesced).
// Sorted Q -> each node's CSR list fills ~ascending in src (convoy).
__global__ __launch_bounds__(256) void build_csr(const unsigned int* __restrict__ pairs,
                                                 const int* __restrict__ bcur,
                                                 int n, int NB,
                                                 int* __restrict__ rowptr,
                                                 int* __restrict__ srcs) {
    int b = blockIdx.x, t = threadIdx.x;
    __shared__ int c[512];
    __shared__ int s2[256];
    __shared__ int sbase, stot;
    __shared__ unsigned int Q[PSTRIDE];    // 18.4 KB sorted bucket
    __shared__ int S[NPB + PSTRIDE];       // 19.4 KB staged srcs segment
    __shared__ int hist[256];
    __shared__ int hcur[256];
    // ---- global bucket-count scan (for CSR base offset) ----
    int c0 = (2 * t < NB) ? min(bcur[2 * t], PSTRIDE) : 0;
    int c1 = (2 * t + 1 < NB) ? min(bcur[2 * t + 1], PSTRIDE) : 0;
    c[2 * t] = c0; c[2 * t + 1] = c1;
    s2[t] = c0 + c1;
    hist[t] = 0;
    __syncthreads();
    for (int o = 1; o < 256; o <<= 1) {
        int u = (t >= o) ? s2[t - o] : 0;
        __syncthreads();
        s2[t] += u;
        __syncthreads();
    }
    if (t == 0) {
        int p = b >> 1;
        int ex = s2[p] - (c[2 * p] + c[2 * p + 1]);
        sbase = ex + ((b & 1) ? c[b & ~1] : 0);
        stot = s2[255];
    }
    __syncthreads();
    int d0 = b << 8;
    int nb = min(NPB, n - d0);
    int cnt_b = c[b];
    int csr0 = sbase + d0;   // pairs before + one self-loop per node before
    const unsigned int* pb = pairs + (size_t)b * PSTRIDE;

    // ---- counting sort by src>>9 into Q ----
    for (int j = t; j < cnt_b; j += 256)
        atomicAdd(&hist[(pb[j] & 0xFFFFFFu) >> 9], 1);   // key <= 195
    __syncthreads();
    int hv = hist[t];
    hcur[t] = hv;
    __syncthreads();
    for (int o = 1; o < 256; o <<= 1) {
        int u = (t >= o) ? hcur[t - o] : 0;
        __syncthreads();
        hcur[t] += u;
        __syncthreads();
    }
    hcur[t] -= hv;                        // exclusive base -> cursor
    __syncthreads();
    for (int j = t; j < cnt_b; j += 256) {
        unsigned int p = pb[j];
        int pos = atomicAdd(&hcur[(p & 0xFFFFFFu) >> 9], 1);
        Q[pos] = p;
    }
    __syncthreads();

    // ---- degree count / scan / fill (into LDS S) from sorted Q ----
    __shared__ int deg[NPB];
    __shared__ int cur[NPB];
    __shared__ int tmp[NPB];
    deg[t] = (t < nb) ? 1 : 0;   // self-loop
    __syncthreads();
    for (int j = t; j < cnt_b; j += 256)
        atomicAdd(&deg[Q[j] >> 24], 1);
    __syncthreads();
    int v = deg[t];
    tmp[t] = v;
    __syncthreads();
    for (int o = 1; o < NPB; o <<= 1) {
        int u = (t >= o) ? tmp[t - o] : 0;
        __syncthreads();
        tmp[t] += u;
        __syncthreads();
    }
    int excl = tmp[t] - v;
    if (t < nb) {
        rowptr[d0 + t] = csr0 + excl;
        S[excl] = d0 + t;             // self-loop at slot 0
        cur[t] = excl + 1;
    }
    __syncthreads();
    // j-round order over sorted Q -> each node's list fills ~ascending in src
    for (int j = t; j < cnt_b; j += 256) {
        unsigned int p = Q[j];
        int off = atomicAdd(&cur[p >> 24], 1);
        S[off] = (int)(p & 0x00FFFFFFu);
    }
    __syncthreads();
    // coalesced flush of the block's whole srcs segment
    int seg = nb + cnt_b;
    for (int j = t; j < seg; j += 256)
        srcs[csr0 + j] = S[j];
    if (b == 0 && t == 0) rowptr[n] = n + stot;
}

// --- tiled node GEMM: 64 nodes x 64 cols per block, 4x4 per thread ----------
// float4-vectorized x staging (R21; a float4 never straddles lim since
// IN_DIM % 4 == 0 and lim is a multiple of IN_DIM).
template <int IN_DIM>
__global__ __launch_bounds__(256) void node_gemm(const float* __restrict__ x,
                                                 const float* __restrict__ W,
                                                 const float* __restrict__ a_src,
                                                 const float* __restrict__ a_dst,
                                                 const float* __restrict__ bias_in,
                                                 float slope_in,
                                                 unsigned short* __restrict__ h16,
                                                 float* __restrict__ al_s,
                                                 float* __restrict__ al_d,
                                                 int n) {
    __shared__ float Ws[IN_DIM * 64];
    __shared__ float xs[IN_DIM][XPAD];
    int t = threadIdx.x;
    int nbase = blockIdx.x * 64;

    for (int idx = t; idx < IN_DIM * 16; idx += 256)
        ((float4*)Ws)[idx] = ((const float4*)W)[idx];
    const float* xb = x + (size_t)nbase * IN_DIM;
    int lim = min(64, n - nbase) * IN_DIM;           // in floats
    constexpr int NV = (64 * IN_DIM) / 4;            // float4 elements
    for (int idx = t; idx < NV; idx += 256) {
        int f0 = idx * 4;
        float4 v = make_float4(0.0f, 0.0f, 0.0f, 0.0f);
        if (f0 < lim) v = ((const float4*)xb)[idx];  // coalesced 16B/lane
        int node = f0 / IN_DIM;
        int k = f0 - node * IN_DIM;
        if (bias_in) {
            v.x += bias_in[k + 0];
            v.y += bias_in[k + 1];
            v.z += bias_in[k + 2];
            v.w += bias_in[k + 3];
            v.x = (v.x >= 0.0f) ? v.x : slope_in * v.x;
            v.y = (v.y >= 0.0f) ? v.y : slope_in * v.y;
            v.z = (v.z >= 0.0f) ? v.z : slope_in * v.z;
            v.w = (v.w >= 0.0f) ? v.w : slope_in * v.w;
        }
        xs[k + 0][node] = v.x;
        xs[k + 1][node] = v.y;
        xs[k + 2][node] = v.z;
        xs[k + 3][node] = v.w;
    }
    __syncthreads();

    int cg = t & 15;    // col group: cols 4cg..4cg+3
    int ng = t >> 4;    // node group: nodes 4ng..4ng+3
    float acc[4][4] = {};
#pragma unroll 8
    for (int k = 0; k < IN_DIM; k++) {
        float4 xv = *(const float4*)&xs[k][ng * 4];
        float4 wv = *(const float4*)&Ws[k * 64 + cg * 4];
        float xa[4] = {xv.x, xv.y, xv.z, xv.w};
        float wa[4] = {wv.x, wv.y, wv.z, wv.w};
#pragma unroll
        for (int i = 0; i < 4; i++)
#pragma unroll
            for (int j = 0; j < 4; j++)
                acc[i][j] += xa[i] * wa[j];
    }

    float4 as4 = *(const float4*)(a_src + cg * 4);
    float4 ad4 = *(const float4*)(a_dst + cg * 4);
#pragma unroll
    for (int i = 0; i < 4; i++) {
        int node = nbase + ng * 4 + i;
        if (node < n) {
            uint2 p;
            p.x = f2bf(acc[i][0]) | (f2bf(acc[i][1]) << 16);
            p.y = f2bf(acc[i][2]) | (f2bf(acc[i][3]) << 16);
            *(uint2*)(h16 + (size_t)node * 64 + cg * 4) = p;
        }
        float vs = acc[i][0] * as4.x + acc[i][1] * as4.y +
                   acc[i][2] * as4.z + acc[i][3] * as4.w;
        float vd = acc[i][0] * ad4.x + acc[i][1] * ad4.y +
                   acc[i][2] * ad4.z + acc[i][3] * ad4.w;
#pragma unroll
        for (int o = 8; o; o >>= 1) {
            vs += __shfl_xor(vs, o);
            vd += __shfl_xor(vd, o);
        }
        if (cg == 0 && node < n) { al_s[node] = vs; al_d[node] = vd; }
    }
}

// --- single-pass aggregate (R17 proven body, BYTE-IDENTICAL): ---------------
// 8 lanes/node, depth-4 prefetch. 53.4us / 32 VGPR / no spill.
// out[node] = (sum_j exp(e_j)*h[src_j]) / (sum_j exp(e_j) + 1e-16)
__device__ __forceinline__ void bf8_fma(float* acc, uint4 q, float w) {
    acc[0] += w * __uint_as_float(q.x << 16);
    acc[1] += w * __uint_as_float(q.x & 0xFFFF0000u);
    acc[2] += w * __uint_as_float(q.y << 16);
    acc[3] += w * __uint_as_float(q.y & 0xFFFF0000u);
    acc[4] += w * __uint_as_float(q.z << 16);
    acc[5] += w * __uint_as_float(q.z & 0xFFFF0000u);
    acc[6] += w * __uint_as_float(q.w << 16);
    acc[7] += w * __uint_as_float(q.w & 0xFFFF0000u);
}

__global__ __launch_bounds__(256) void gat_aggregate(const int* __restrict__ rowptr,
                                                     const int* __restrict__ srcs,
                                                     const float* __restrict__ als,
                                                     const float* __restrict__ ald,
                                                     const unsigned short* __restrict__ h16,
                                                     float* __restrict__ hout,
                                                     int n) {
    int t = threadIdx.x;
    int sub = t >> 3, lane = t & 7;       // 32 nodes/block, 8 lanes/node
    int node = blockIdx.x * 32 + sub;
    if (node >= n) return;
    int beg = rowptr[node], end = rowptr[node + 1];
    float aldv = ald[node];
    const unsigned short* hb = h16 + lane * 8;

    float acc[8] = {};
    float sm = 0.0f;
    int j = beg;
    if (j + 4 <= end) {
        int s0 = srcs[j], s1 = srcs[j + 1], s2 = srcs[j + 2], s3 = srcs[j + 3];
        for (; j + 8 <= end; j += 4) {
            // prefetch next quad's indices: breaks srcs->gather serial chain
            int n0 = srcs[j + 4], n1 = srcs[j + 5];
            int n2 = srcs[j + 6], n3 = srcs[j + 7];
            float e0 = als[s0] + aldv, e1 = als[s1] + aldv;
            float e2 = als[s2] + aldv, e3 = als[s3] + aldv;
            uint4 q0 = *(const uint4*)(hb + (size_t)s0 * 64);
            uint4 q1 = *(const uint4*)(hb + (size_t)s1 * 64);
            uint4 q2 = *(const uint4*)(hb + (size_t)s2 * 64);
            uint4 q3 = *(const uint4*)(hb + (size_t)s3 * 64);
            e0 = (e0 >= 0.0f) ? e0 : 0.2f * e0;
            e1 = (e1 >= 0.0f) ? e1 : 0.2f * e1;
            e2 = (e2 >= 0.0f) ? e2 : 0.2f * e2;
            e3 = (e3 >= 0.0f) ? e3 : 0.2f * e3;
            float w0 = __expf(e0), w1 = __expf(e1);
            float w2 = __expf(e2), w3 = __expf(e3);
            sm += (w0 + w1) + (w2 + w3);
            bf8_fma(acc, q0, w0);
            bf8_fma(acc, q1, w1);
            bf8_fma(acc, q2, w2);
            bf8_fma(acc, q3, w3);
            s0 = n0; s1 = n1; s2 = n2; s3 = n3;
        }
        // final full quad (s0..s3 already loaded)
        {
            float e0 = als[s0] + aldv, e1 = als[s1] + aldv;
            float e2 = als[s2] + aldv, e3 = als[s3] + aldv;
            uint4 q0 = *(const uint4*)(hb + (size_t)s0 * 64);
            uint4 q1 = *(const uint4*)(hb + (size_t)s1 * 64);
            uint4 q2 = *(const uint4*)(hb + (size_t)s2 * 64);
            uint4 q3 = *(const uint4*)(hb + (size_t)s3 * 64);
            e0 = (e0 >= 0.0f) ? e0 : 0.2f * e0;
            e1 = (e1 >= 0.0f) ? e1 : 0.2f * e1;
            e2 = (e2 >= 0.0f) ? e2 : 0.2f * e2;
            e3 = (e3 >= 0.0f) ? e3 : 0.2f * e3;
            float w0 = __expf(e0), w1 = __expf(e1);
            float w2 = __expf(e2), w3 = __expf(e3);
            sm += (w0 + w1) + (w2 + w3);
            bf8_fma(acc, q0, w0);
            bf8_fma(acc, q1, w1);
            bf8_fma(acc, q2, w2);
            bf8_fma(acc, q3, w3);
            j += 4;
        }
    }
    for (; j < end; j++) {
        int s = srcs[j];
        float e = als[s] + aldv;
        e = (e >= 0.0f) ? e : 0.2f * e;
        float w = __expf(e);
        uint4 q = *(const uint4*)(hb + (size_t)s * 64);
        sm += w;
        bf8_fma(acc, q, w);
    }

    float inv = 1.0f / (sm + 1e-16f);
    float4 o0 = make_float4(acc[0] * inv, acc[1] * inv, acc[2] * inv, acc[3] * inv);
    float4 o1 = make_float4(acc[4] * inv, acc[5] * inv, acc[6] * inv, acc[7] * inv);
    float* op = hout + (size_t)node * 64 + lane * 8;
    *(float4*)op = o0;
    *(float4*)(op + 4) = o1;
}

// --- fused pool + FC: one block per graph, binary-search batch bounds -------
__global__ __launch_bounds__(256) void pool_fc(const float* __restrict__ hout,
                                               const float* __restrict__ b2,
                                               const int* __restrict__ batch,
                                               const float* __restrict__ fcW,
                                               const float* __restrict__ fcb,
                                               float* __restrict__ out, int n) {
    int g = blockIdx.x;
    int t = threadIdx.x;
    __shared__ int sLo, sHi;
    __shared__ float red[4][64];
    if (t == 0) {
        int lo = 0, hi = n;
        while (lo < hi) { int m = (lo + hi) >> 1; if (batch[m] < g) lo = m + 1; else hi = m; }
        sLo = lo;
    } else if (t == 64) {
        int lo = 0, hi = n;
        while (lo < hi) { int m = (lo + hi) >> 1; if (batch[m] < g + 1) lo = m + 1; else hi = m; }
        sHi = lo;
    }
    __syncthreads();
    int lo = sLo, hi = sHi;
    int wv = t >> 6, lane = t & 63;
    float acc = 0.0f;
    for (int node = lo + wv; node < hi; node += 4)
        acc += hout[(size_t)node * 64 + lane];
    red[wv][lane] = acc;
    __syncthreads();
    if (wv == 0) {
        float c = (float)(hi - lo);
        float s = red[0][lane] + red[1][lane] + red[2][lane] + red[3][lane];
        s += c * b2[lane];
        float cd = (c > 1.0f) ? c : 1.0f;
        float p = s / cd;
        float s0 = p * fcW[lane * 2 + 0];
        float s1 = p * fcW[lane * 2 + 1];
#pragma unroll
        for (int o = 32; o; o >>= 1) {
            s0 += __shfl_xor(s0, o);
            s1 += __shfl_xor(s1, o);
        }
        if (lane == 0) {
            out[g * 2 + 0] = s0 + fcb[0];
            out[g * 2 + 1] = s1 + fcb[1];
        }
    }
}

extern "C" void kernel_launch(void* const* d_in, const int* in_sizes, int n_in,
                              void* d_out, int out_size, void* d_ws, size_t ws_size,
                              hipStream_t stream) {
    const float* x    = (const float*)d_in[0];
    const int*   ei   = (const int*)d_in[1];
    const int*   batch= (const int*)d_in[2];
    const float* W1   = (const float*)d_in[3];
    const float* as1  = (const float*)d_in[4];
    const float* ad1  = (const float*)d_in[5];
    const float* b1   = (const float*)d_in[6];
    const float* W2   = (const float*)d_in[7];
    const float* as2  = (const float*)d_in[8];
    const float* ad2  = (const float*)d_in[9];
    const float* b2   = (const float*)d_in[10];
    const float* fcW  = (const float*)d_in[11];
    const float* fcb  = (const float*)d_in[12];
    float* out = (float*)d_out;

    const int N = in_sizes[2];       // 100000
    const int E = in_sizes[1] / 2;   // 1600000
    const int G = out_size / 2;      // 256
    const int tot = E + N;
    const int NB = (N + NPB - 1) / NPB;   // 391 buckets

    // ws layout (~46 MiB): pairs ALIASES bufO (disjoint lifetimes:
    // pairs die at build_csr; bufO first written by aggregate layer 1).
    float* ws     = (float*)d_ws;
    float* bufO   = ws;                                  // N*64 fp32  25.6 MB
    unsigned int* pairs  = (unsigned int*)bufO;          // alias      7.2 MB
    float* als    = bufO + (size_t)N * 64;               // N          0.4 MB
    float* ald    = als + N;                             // N          0.4 MB
    int*   rowptr = (int*)(ald + N);                     // N+1        0.4 MB
    int*   srcs   = rowptr + N + 1;                      // tot        6.8 MB
    int*   bcur   = srcs + tot;                          // NB
    unsigned short* bufH16 = (unsigned short*)(bcur + NB);  // N*64   12.8 MB

    dim3 b256(256);
    int gInit = (NB + 255) / 256;
    int gPart = (E + EPB - 1) / EPB;
    int gGemm = (N + 63) / 64;
    int gAgg  = (N + 31) / 32;

    // ---- CSR build: partition + fused sort/fill (both LDS-staged) ----------
    init_all<<<gInit, b256, 0, stream>>>(bcur, NB);
    partition<<<gPart, b256, 0, stream>>>(ei, E, NB, bcur, pairs);
    build_csr<<<NB, b256, 0, stream>>>(pairs, bcur, N, NB, rowptr, srcs);

    // ---- layer 1 ----
    node_gemm<72><<<gGemm, b256, 0, stream>>>(x, W1, as1, ad1, nullptr, 0.0f,
                                              bufH16, als, ald, N);
    gat_aggregate<<<gAgg, b256, 0, stream>>>(rowptr, srcs, als, ald, bufH16, bufO, N);

    // ---- layer 2 (input = leaky(bufO + b1, 0.01)) ----
    node_gemm<64><<<gGemm, b256, 0, stream>>>(bufO, W2, as2, ad2, b1, 0.01f,
                                              bufH16, als, ald, N);
    gat_aggregate<<<gAgg, b256, 0, stream>>>(rowptr, srcs, als, ald, bufH16, bufO, N);

    // ---- fused pool + fc ----
    pool_fc<<<G, b256, 0, stream>>>(bufO, b2, batch, fcW, fcb, out, N);
}

// Round 16
// 296.209 us; speedup vs baseline: 1.0818x; 1.0487x over previous
//
#include <hip/hip_runtime.h>
#include <hip/hip_bf16.h>
#include <math.h>

// ---------------------------------------------------------------------------
// GAT: 2x GATConv(heads=1) + global mean pool + FC(64->2)
// R27 = R26 (best, 310.6us) + two safe skims:
//   (1) init_all kernel deleted -> hipMemsetAsync(bcur) (one fewer launch;
//       memsetAsync is stream-ordered + graph-capturable, G9 allows it).
//   (2) pool_fc reads hout as float4 (16 lanes x 4 floats/row, 16 nodes
//       per iteration) -> full-width BW on the 25.6MB scan.
//   All other kernels BYTE-IDENTICAL to R26 (aggregate = R17 body;
//   partition/build_csr = R26 LDS-staged coalesced flush; gemm = R21).
// ---------------------------------------------------------------------------

#define NPB 256          // nodes per bucket
#define EPB 4096         // edges per partition block (256 thr x 16)
#define PSTRIDE 4608     // slots per bucket (lambda=4092, +8 sigma)
#define XPAD 68          // xs leading-dim pad: 8-way banks, 16B-aligned rows

__device__ __forceinline__ unsigned int f2bf(float v) {
    unsigned int b = __float_as_uint(v);
    b += 0x7FFFu + ((b >> 16) & 1u);   // round-to-nearest-even
    return b >> 16;
}

// --- partition edges into fixed-stride dst-buckets (packed uint32) ----------
// LDS-staged coalesced flush (R26). int4 edge loads (R24).
__global__ __launch_bounds__(256) void partition(const int* __restrict__ ei,
                                                 int E, int NB,
                                                 int* __restrict__ bcur,
                                                 unsigned int* __restrict__ pairs) {
    __shared__ int h[512];                 // per-bucket counts
    __shared__ int ls[512];                // exclusive local starts
    __shared__ int lcur[512];              // scatter cursors
    __shared__ int hb[512];                // global bases
    __shared__ int s2[256];
    __shared__ unsigned int Qp[EPB];       // 16 KB staged vals
    __shared__ unsigned short Bq[EPB];     // 8 KB bucket ids
    int t = threadIdx.x;
    for (int i = t; i < 512; i += 256) h[i] = 0;
    __syncthreads();
    int i0 = blockIdx.x * EPB;
    unsigned int val[16];
    int bk[16];
    const int4* s4p = (const int4*)(ei);
    const int4* d4p = (const int4*)(ei + E);
#pragma unroll
    for (int k = 0; k < 4; k++) {
        int vbase = (i0 >> 2) + k * 256 + t;   // int4 index
        int i = vbase << 2;
        if (i < E) {                           // E%4==0 -> whole int4 valid
            int4 s4 = s4p[vbase];
            int4 d4 = d4p[vbase];
            int ss[4] = {s4.x, s4.y, s4.z, s4.w};
            int dd[4] = {d4.x, d4.y, d4.z, d4.w};
#pragma unroll
            for (int j = 0; j < 4; j++) {
                int e = k * 4 + j;
                bk[e] = dd[j] >> 8;
                val[e] = (unsigned)ss[j] | ((unsigned)(dd[j] & 255) << 24);
                atomicAdd(&h[bk[e]], 1);
            }
        } else {
#pragma unroll
            for (int j = 0; j < 4; j++) bk[k * 4 + j] = -1;
        }
    }
    __syncthreads();
    // exclusive scan of h[0..511] -> ls (pairwise, 256 threads)
    int p0 = h[2 * t], p1 = h[2 * t + 1];
    s2[t] = p0 + p1;
    __syncthreads();
    for (int o = 1; o < 256; o <<= 1) {
        int u = (t >= o) ? s2[t - o] : 0;
        __syncthreads();
        s2[t] += u;
        __syncthreads();
    }
    int ex = s2[t] - p0 - p1;
    ls[2 * t] = ex;           ls[2 * t + 1] = ex + p0;
    lcur[2 * t] = ex;         lcur[2 * t + 1] = ex + p0;
    __syncthreads();
    // global bases (one atomic per non-empty bucket)
    for (int b = t; b < NB; b += 256)
        hb[b] = h[b] ? atomicAdd(&bcur[b], h[b]) : 0;
    __syncthreads();
    // LDS scatter by local rank
#pragma unroll
    for (int e = 0; e < 16; e++) {
        if (bk[e] < 0) continue;
        int pos = atomicAdd(&lcur[bk[e]], 1);
        Qp[pos] = val[e];
        Bq[pos] = (unsigned short)bk[e];
    }
    __syncthreads();
    // linear flush: consecutive j -> same bucket -> adjacent global slots
    int total = s2[255];
    for (int j = t; j < total; j += 256) {
        int bkj = Bq[j];
        int gp = hb[bkj] + (j - ls[bkj]);
        if (gp < PSTRIDE)                  // overflow guard (stat. impossible)
            pairs[(size_t)bkj * PSTRIDE + gp] = Qp[j];
    }
}

// --- per-bucket CSR fill with FUSED counting sort by src>>9 -----------------
// srcs segment built in LDS S[] then flushed linearly (coalesced, R26).
// Sorted Q -> each node's CSR list fills ~ascending in src (convoy).
__global__ __launch_bounds__(256) void build_csr(const unsigned int* __restrict__ pairs,
                                                 const int* __restrict__ bcur,
                                                 int n, int NB,
                                                 int* __restrict__ rowptr,
                                                 int* __restrict__ srcs) {
    int b = blockIdx.x, t = threadIdx.x;
    __shared__ int c[512];
    __shared__ int s2[256];
    __shared__ int sbase, stot;
    __shared__ unsigned int Q[PSTRIDE];    // 18.4 KB sorted bucket
    __shared__ int S[NPB + PSTRIDE];       // 19.4 KB staged srcs segment
    __shared__ int hist[256];
    __shared__ int hcur[256];
    // ---- global bucket-count scan (for CSR base offset) ----
    int c0 = (2 * t < NB) ? min(bcur[2 * t], PSTRIDE) : 0;
    int c1 = (2 * t + 1 < NB) ? min(bcur[2 * t + 1], PSTRIDE) : 0;
    c[2 * t] = c0; c[2 * t + 1] = c1;
    s2[t] = c0 + c1;
    hist[t] = 0;
    __syncthreads();
    for (int o = 1; o < 256; o <<= 1) {
        int u = (t >= o) ? s2[t - o] : 0;
        __syncthreads();
        s2[t] += u;
        __syncthreads();
    }
    if (t == 0) {
        int p = b >> 1;
        int ex = s2[p] - (c[2 * p] + c[2 * p + 1]);
        sbase = ex + ((b & 1) ? c[b & ~1] : 0);
        stot = s2[255];
    }
    __syncthreads();
    int d0 = b << 8;
    int nb = min(NPB, n - d0);
    int cnt_b = c[b];
    int csr0 = sbase + d0;   // pairs before + one self-loop per node before
    const unsigned int* pb = pairs + (size_t)b * PSTRIDE;

    // ---- counting sort by src>>9 into Q ----
    for (int j = t; j < cnt_b; j += 256)
        atomicAdd(&hist[(pb[j] & 0xFFFFFFu) >> 9], 1);   // key <= 195
    __syncthreads();
    int hv = hist[t];
    hcur[t] = hv;
    __syncthreads();
    for (int o = 1; o < 256; o <<= 1) {
        int u = (t >= o) ? hcur[t - o] : 0;
        __syncthreads();
        hcur[t] += u;
        __syncthreads();
    }
    hcur[t] -= hv;                        // exclusive base -> cursor
    __syncthreads();
    for (int j = t; j < cnt_b; j += 256) {
        unsigned int p = pb[j];
        int pos = atomicAdd(&hcur[(p & 0xFFFFFFu) >> 9], 1);
        Q[pos] = p;
    }
    __syncthreads();

    // ---- degree count / scan / fill (into LDS S) from sorted Q ----
    __shared__ int deg[NPB];
    __shared__ int cur[NPB];
    __shared__ int tmp[NPB];
    deg[t] = (t < nb) ? 1 : 0;   // self-loop
    __syncthreads();
    for (int j = t; j < cnt_b; j += 256)
        atomicAdd(&deg[Q[j] >> 24], 1);
    __syncthreads();
    int v = deg[t];
    tmp[t] = v;
    __syncthreads();
    for (int o = 1; o < NPB; o <<= 1) {
        int u = (t >= o) ? tmp[t - o] : 0;
        __syncthreads();
        tmp[t] += u;
        __syncthreads();
    }
    int excl = tmp[t] - v;
    if (t < nb) {
        rowptr[d0 + t] = csr0 + excl;
        S[excl] = d0 + t;             // self-loop at slot 0
        cur[t] = excl + 1;
    }
    __syncthreads();
    // j-round order over sorted Q -> each node's list fills ~ascending in src
    for (int j = t; j < cnt_b; j += 256) {
        unsigned int p = Q[j];
        int off = atomicAdd(&cur[p >> 24], 1);
        S[off] = (int)(p & 0x00FFFFFFu);
    }
    __syncthreads();
    // coalesced flush of the block's whole srcs segment
    int seg = nb + cnt_b;
    for (int j = t; j < seg; j += 256)
        srcs[csr0 + j] = S[j];
    if (b == 0 && t == 0) rowptr[n] = n + stot;
}

// --- tiled node GEMM: 64 nodes x 64 cols per block, 4x4 per thread ----------
// float4-vectorized x staging (R21; a float4 never straddles lim since
// IN_DIM % 4 == 0 and lim is a multiple of IN_DIM).
template <int IN_DIM>
__global__ __launch_bounds__(256) void node_gemm(const float* __restrict__ x,
                                                 const float* __restrict__ W,
                                                 const float* __restrict__ a_src,
                                                 const float* __restrict__ a_dst,
                                                 const float* __restrict__ bias_in,
                                                 float slope_in,
                                                 unsigned short* __restrict__ h16,
                                                 float* __restrict__ al_s,
                                                 float* __restrict__ al_d,
                                                 int n) {
    __shared__ float Ws[IN_DIM * 64];
    __shared__ float xs[IN_DIM][XPAD];
    int t = threadIdx.x;
    int nbase = blockIdx.x * 64;

    for (int idx = t; idx < IN_DIM * 16; idx += 256)
        ((float4*)Ws)[idx] = ((const float4*)W)[idx];
    const float* xb = x + (size_t)nbase * IN_DIM;
    int lim = min(64, n - nbase) * IN_DIM;           // in floats
    constexpr int NV = (64 * IN_DIM) / 4;            // float4 elements
    for (int idx = t; idx < NV; idx += 256) {
        int f0 = idx * 4;
        float4 v = make_float4(0.0f, 0.0f, 0.0f, 0.0f);
        if (f0 < lim) v = ((const float4*)xb)[idx];  // coalesced 16B/lane
        int node = f0 / IN_DIM;
        int k = f0 - node * IN_DIM;
        if (bias_in) {
            v.x += bias_in[k + 0];
            v.y += bias_in[k + 1];
            v.z += bias_in[k + 2];
            v.w += bias_in[k + 3];
            v.x = (v.x >= 0.0f) ? v.x : slope_in * v.x;
            v.y = (v.y >= 0.0f) ? v.y : slope_in * v.y;
            v.z = (v.z >= 0.0f) ? v.z : slope_in * v.z;
            v.w = (v.w >= 0.0f) ? v.w : slope_in * v.w;
        }
        xs[k + 0][node] = v.x;
        xs[k + 1][node] = v.y;
        xs[k + 2][node] = v.z;
        xs[k + 3][node] = v.w;
    }
    __syncthreads();

    int cg = t & 15;    // col group: cols 4cg..4cg+3
    int ng = t >> 4;    // node group: nodes 4ng..4ng+3
    float acc[4][4] = {};
#pragma unroll 8
    for (int k = 0; k < IN_DIM; k++) {
        float4 xv = *(const float4*)&xs[k][ng * 4];
        float4 wv = *(const float4*)&Ws[k * 64 + cg * 4];
        float xa[4] = {xv.x, xv.y, xv.z, xv.w};
        float wa[4] = {wv.x, wv.y, wv.z, wv.w};
#pragma unroll
        for (int i = 0; i < 4; i++)
#pragma unroll
            for (int j = 0; j < 4; j++)
                acc[i][j] += xa[i] * wa[j];
    }

    float4 as4 = *(const float4*)(a_src + cg * 4);
    float4 ad4 = *(const float4*)(a_dst + cg * 4);
#pragma unroll
    for (int i = 0; i < 4; i++) {
        int node = nbase + ng * 4 + i;
        if (node < n) {
            uint2 p;
            p.x = f2bf(acc[i][0]) | (f2bf(acc[i][1]) << 16);
            p.y = f2bf(acc[i][2]) | (f2bf(acc[i][3]) << 16);
            *(uint2*)(h16 + (size_t)node * 64 + cg * 4) = p;
        }
        float vs = acc[i][0] * as4.x + acc[i][1] * as4.y +
                   acc[i][2] * as4.z + acc[i][3] * as4.w;
        float vd = acc[i][0] * ad4.x + acc[i][1] * ad4.y +
                   acc[i][2] * ad4.z + acc[i][3] * ad4.w;
#pragma unroll
        for (int o = 8; o; o >>= 1) {
            vs += __shfl_xor(vs, o);
            vd += __shfl_xor(vd, o);
        }
        if (cg == 0 && node < n) { al_s[node] = vs; al_d[node] = vd; }
    }
}

// --- single-pass aggregate (R17 proven body, BYTE-IDENTICAL): ---------------
// 8 lanes/node, depth-4 prefetch. 53.4us / 32 VGPR / no spill.
// out[node] = (sum_j exp(e_j)*h[src_j]) / (sum_j exp(e_j) + 1e-16)
__device__ __forceinline__ void bf8_fma(float* acc, uint4 q, float w) {
    acc[0] += w * __uint_as_float(q.x << 16);
    acc[1] += w * __uint_as_float(q.x & 0xFFFF0000u);
    acc[2] += w * __uint_as_float(q.y << 16);
    acc[3] += w * __uint_as_float(q.y & 0xFFFF0000u);
    acc[4] += w * __uint_as_float(q.z << 16);
    acc[5] += w * __uint_as_float(q.z & 0xFFFF0000u);
    acc[6] += w * __uint_as_float(q.w << 16);
    acc[7] += w * __uint_as_float(q.w & 0xFFFF0000u);
}

__global__ __launch_bounds__(256) void gat_aggregate(const int* __restrict__ rowptr,
                                                     const int* __restrict__ srcs,
                                                     const float* __restrict__ als,
                                                     const float* __restrict__ ald,
                                                     const unsigned short* __restrict__ h16,
                                                     float* __restrict__ hout,
                                                     int n) {
    int t = threadIdx.x;
    int sub = t >> 3, lane = t & 7;       // 32 nodes/block, 8 lanes/node
    int node = blockIdx.x * 32 + sub;
    if (node >= n) return;
    int beg = rowptr[node], end = rowptr[node + 1];
    float aldv = ald[node];
    const unsigned short* hb = h16 + lane * 8;

    float acc[8] = {};
    float sm = 0.0f;
    int j = beg;
    if (j + 4 <= end) {
        int s0 = srcs[j], s1 = srcs[j + 1], s2 = srcs[j + 2], s3 = srcs[j + 3];
        for (; j + 8 <= end; j += 4) {
            // prefetch next quad's indices: breaks srcs->gather serial chain
            int n0 = srcs[j + 4], n1 = srcs[j + 5];
            int n2 = srcs[j + 6], n3 = srcs[j + 7];
            float e0 = als[s0] + aldv, e1 = als[s1] + aldv;
            float e2 = als[s2] + aldv, e3 = als[s3] + aldv;
            uint4 q0 = *(const uint4*)(hb + (size_t)s0 * 64);
            uint4 q1 = *(const uint4*)(hb + (size_t)s1 * 64);
            uint4 q2 = *(const uint4*)(hb + (size_t)s2 * 64);
            uint4 q3 = *(const uint4*)(hb + (size_t)s3 * 64);
            e0 = (e0 >= 0.0f) ? e0 : 0.2f * e0;
            e1 = (e1 >= 0.0f) ? e1 : 0.2f * e1;
            e2 = (e2 >= 0.0f) ? e2 : 0.2f * e2;
            e3 = (e3 >= 0.0f) ? e3 : 0.2f * e3;
            float w0 = __expf(e0), w1 = __expf(e1);
            float w2 = __expf(e2), w3 = __expf(e3);
            sm += (w0 + w1) + (w2 + w3);
            bf8_fma(acc, q0, w0);
            bf8_fma(acc, q1, w1);
            bf8_fma(acc, q2, w2);
            bf8_fma(acc, q3, w3);
            s0 = n0; s1 = n1; s2 = n2; s3 = n3;
        }
        // final full quad (s0..s3 already loaded)
        {
            float e0 = als[s0] + aldv, e1 = als[s1] + aldv;
            float e2 = als[s2] + aldv, e3 = als[s3] + aldv;
            uint4 q0 = *(const uint4*)(hb + (size_t)s0 * 64);
            uint4 q1 = *(const uint4*)(hb + (size_t)s1 * 64);
            uint4 q2 = *(const uint4*)(hb + (size_t)s2 * 64);
            uint4 q3 = *(const uint4*)(hb + (size_t)s3 * 64);
            e0 = (e0 >= 0.0f) ? e0 : 0.2f * e0;
            e1 = (e1 >= 0.0f) ? e1 : 0.2f * e1;
            e2 = (e2 >= 0.0f) ? e2 : 0.2f * e2;
            e3 = (e3 >= 0.0f) ? e3 : 0.2f * e3;
            float w0 = __expf(e0), w1 = __expf(e1);
            float w2 = __expf(e2), w3 = __expf(e3);
            sm += (w0 + w1) + (w2 + w3);
            bf8_fma(acc, q0, w0);
            bf8_fma(acc, q1, w1);
            bf8_fma(acc, q2, w2);
            bf8_fma(acc, q3, w3);
            j += 4;
        }
    }
    for (; j < end; j++) {
        int s = srcs[j];
        float e = als[s] + aldv;
        e = (e >= 0.0f) ? e : 0.2f * e;
        float w = __expf(e);
        uint4 q = *(const uint4*)(hb + (size_t)s * 64);
        sm += w;
        bf8_fma(acc, q, w);
    }

    float inv = 1.0f / (sm + 1e-16f);
    float4 o0 = make_float4(acc[0] * inv, acc[1] * inv, acc[2] * inv, acc[3] * inv);
    float4 o1 = make_float4(acc[4] * inv, acc[5] * inv, acc[6] * inv, acc[7] * inv);
    float* op = hout + (size_t)node * 64 + lane * 8;
    *(float4*)op = o0;
    *(float4*)(op + 4) = o1;
}

// --- fused pool + FC: one block per graph, float4 hout reads ----------------
__global__ __launch_bounds__(256) void pool_fc(const float* __restrict__ hout,
                                               const float* __restrict__ b2,
                                               const int* __restrict__ batch,
                                               const float* __restrict__ fcW,
                                               const float* __restrict__ fcb,
                                               float* __restrict__ out, int n) {
    int g = blockIdx.x;
    int t = threadIdx.x;
    __shared__ int sLo, sHi;
    __shared__ float red[16][64];
    if (t == 0) {
        int lo = 0, hi = n;
        while (lo < hi) { int m = (lo + hi) >> 1; if (batch[m] < g) lo = m + 1; else hi = m; }
        sLo = lo;
    } else if (t == 64) {
        int lo = 0, hi = n;
        while (lo < hi) { int m = (lo + hi) >> 1; if (batch[m] < g + 1) lo = m + 1; else hi = m; }
        sHi = lo;
    }
    __syncthreads();
    int lo = sLo, hi = sHi;
    int q = t & 15;     // float4 index within 64-float row
    int r = t >> 4;     // node offset (stride 16)
    float4 a4 = make_float4(0.0f, 0.0f, 0.0f, 0.0f);
    for (int node = lo + r; node < hi; node += 16) {
        float4 v = *(const float4*)(hout + (size_t)node * 64 + q * 4);
        a4.x += v.x; a4.y += v.y; a4.z += v.z; a4.w += v.w;
    }
    *(float4*)&red[r][q * 4] = a4;
    __syncthreads();
    if (t < 64) {
        float c = (float)(hi - lo);
        float s = 0.0f;
#pragma unroll
        for (int i = 0; i < 16; i++) s += red[i][t];
        s += c * b2[t];
        float cd = (c > 1.0f) ? c : 1.0f;
        float p = s / cd;
        float s0 = p * fcW[t * 2 + 0];
        float s1 = p * fcW[t * 2 + 1];
#pragma unroll
        for (int o = 32; o; o >>= 1) {
            s0 += __shfl_xor(s0, o);
            s1 += __shfl_xor(s1, o);
        }
        if (t == 0) {
            out[g * 2 + 0] = s0 + fcb[0];
            out[g * 2 + 1] = s1 + fcb[1];
        }
    }
}

extern "C" void kernel_launch(void* const* d_in, const int* in_sizes, int n_in,
                              void* d_out, int out_size, void* d_ws, size_t ws_size,
                              hipStream_t stream) {
    const float* x    = (const float*)d_in[0];
    const int*   ei   = (const int*)d_in[1];
    const int*   batch= (const int*)d_in[2];
    const float* W1   = (const float*)d_in[3];
    const float* as1  = (const float*)d_in[4];
    const float* ad1  = (const float*)d_in[5];
    const float* b1   = (const float*)d_in[6];
    const float* W2   = (const float*)d_in[7];
    const float* as2  = (const float*)d_in[8];
    const float* ad2  = (const float*)d_in[9];
    const float* b2   = (const float*)d_in[10];
    const float* fcW  = (const float*)d_in[11];
    const float* fcb  = (const float*)d_in[12];
    float* out = (float*)d_out;

    const int N = in_sizes[2];       // 100000
    const int E = in_sizes[1] / 2;   // 1600000
    const int G = out_size / 2;      // 256
    const int tot = E + N;
    const int NB = (N + NPB - 1) / NPB;   // 391 buckets

    // ws layout (~46 MiB): pairs ALIASES bufO (disjoint lifetimes:
    // pairs die at build_csr; bufO first written by aggregate layer 1).
    float* ws     = (float*)d_ws;
    float* bufO   = ws;                                  // N*64 fp32  25.6 MB
    unsigned int* pairs  = (unsigned int*)bufO;          // alias      7.2 MB
    float* als    = bufO + (size_t)N * 64;               // N          0.4 MB
    float* ald    = als + N;                             // N          0.4 MB
    int*   rowptr = (int*)(ald + N);                     // N+1        0.4 MB
    int*   srcs   = rowptr + N + 1;                      // tot        6.8 MB
    int*   bcur   = srcs + tot;                          // NB
    unsigned short* bufH16 = (unsigned short*)(bcur + NB);  // N*64   12.8 MB

    dim3 b256(256);
    int gPart = (E + EPB - 1) / EPB;
    int gGemm = (N + 63) / 64;
    int gAgg  = (N + 31) / 32;

    // ---- CSR build: memset cursors + partition + fused sort/fill -----------
    hipMemsetAsync(bcur, 0, (size_t)NB * sizeof(int), stream);
    partition<<<gPart, b256, 0, stream>>>(ei, E, NB, bcur, pairs);
    build_csr<<<NB, b256, 0, stream>>>(pairs, bcur, N, NB, rowptr, srcs);

    // ---- layer 1 ----
    node_gemm<72><<<gGemm, b256, 0, stream>>>(x, W1, as1, ad1, nullptr, 0.0f,
                                              bufH16, als, ald, N);
    gat_aggregate<<<gAgg, b256, 0, stream>>>(rowptr, srcs, als, ald, bufH16, bufO, N);

    // ---- layer 2 (input = leaky(bufO + b1, 0.01)) ----
    node_gemm<64><<<gGemm, b256, 0, stream>>>(bufO, W2, as2, ad2, b1, 0.01f,
                                              bufH16, als, ald, N);
    gat_aggregate<<<gAgg, b256, 0, stream>>>(rowptr, srcs, als, ald, bufH16, bufO, N);

    // ---- fused pool + fc ----
    pool_fc<<<G, b256, 0, stream>>>(bufO, b2, batch, fcW, fcb, out, N);
}

// Round 17
// 294.469 us; speedup vs baseline: 1.0882x; 1.0059x over previous
//
#include <hip/hip_runtime.h>
#include <hip/hip_bf16.h>
#include <math.h>

// ---------------------------------------------------------------------------
// GAT: 2x GATConv(heads=1) + global mean pool + FC(64->2)
// R28 = R27 (best, 296.2us) + shuffle-based prefix scans in partition &
//       build_csr.
//   R27 post-mortem: launch/small-kernel overhead is real (-14.4us from
//   memset + float4 pool_fc). Next: the serial barrier chains. Each 256-wide
//   LDS scan was 8 rounds x 2 barriers; build_csr has THREE (54 barriers/
//   block), partition one. Replaced by wave64 __shfl_up scan + 4-entry
//   cross-wave combine = 2 barriers each (-42/block csr, -14 partition).
//   Aggregate / node_gemm / pool_fc BYTE-IDENTICAL to R27.
// ---------------------------------------------------------------------------

#define NPB 256          // nodes per bucket
#define EPB 4096         // edges per partition block (256 thr x 16)
#define PSTRIDE 4608     // slots per bucket (lambda=4092, +8 sigma)
#define XPAD 68          // xs leading-dim pad: 8-way banks, 16B-aligned rows

__device__ __forceinline__ unsigned int f2bf(float v) {
    unsigned int b = __float_as_uint(v);
    b += 0x7FFFu + ((b >> 16) & 1u);   // round-to-nearest-even
    return b >> 16;
}

// inclusive scan of one value per thread across 256 threads: wave64 shuffle
// scan + cross-wave combine via 4-entry LDS. Exactly 2 __syncthreads().
__device__ __forceinline__ int scanIncl256(int v, int t, int* wsum) {
    int lane = t & 63, wv = t >> 6;
#pragma unroll
    for (int o = 1; o < 64; o <<= 1) {
        int u = __shfl_up(v, o);
        if (lane >= o) v += u;
    }
    if (lane == 63) wsum[wv] = v;
    __syncthreads();
    int base = 0;
#pragma unroll
    for (int i = 0; i < 3; i++) base += (i < wv) ? wsum[i] : 0;
    __syncthreads();                     // guards wsum reuse by next call
    return v + base;
}

// --- partition edges into fixed-stride dst-buckets (packed uint32) ----------
// LDS-staged coalesced flush (R26). int4 edge loads (R24). Shuffle scan (R28).
__global__ __launch_bounds__(256) void partition(const int* __restrict__ ei,
                                                 int E, int NB,
                                                 int* __restrict__ bcur,
                                                 unsigned int* __restrict__ pairs) {
    __shared__ int h[512];                 // per-bucket counts
    __shared__ int ls[512];                // exclusive local starts
    __shared__ int lcur[512];              // scatter cursors
    __shared__ int hb[512];                // global bases
    __shared__ int s2[256];
    __shared__ int wsum[4];
    __shared__ unsigned int Qp[EPB];       // 16 KB staged vals
    __shared__ unsigned short Bq[EPB];     // 8 KB bucket ids
    int t = threadIdx.x;
    for (int i = t; i < 512; i += 256) h[i] = 0;
    __syncthreads();
    int i0 = blockIdx.x * EPB;
    unsigned int val[16];
    int bk[16];
    const int4* s4p = (const int4*)(ei);
    const int4* d4p = (const int4*)(ei + E);
#pragma unroll
    for (int k = 0; k < 4; k++) {
        int vbase = (i0 >> 2) + k * 256 + t;   // int4 index
        int i = vbase << 2;
        if (i < E) {                           // E%4==0 -> whole int4 valid
            int4 s4 = s4p[vbase];
            int4 d4 = d4p[vbase];
            int ss[4] = {s4.x, s4.y, s4.z, s4.w};
            int dd[4] = {d4.x, d4.y, d4.z, d4.w};
#pragma unroll
            for (int j = 0; j < 4; j++) {
                int e = k * 4 + j;
                bk[e] = dd[j] >> 8;
                val[e] = (unsigned)ss[j] | ((unsigned)(dd[j] & 255) << 24);
                atomicAdd(&h[bk[e]], 1);
            }
        } else {
#pragma unroll
            for (int j = 0; j < 4; j++) bk[k * 4 + j] = -1;
        }
    }
    __syncthreads();
    // exclusive scan of h[0..511] via pairwise shuffle scan (2 barriers)
    int p0 = h[2 * t], p1 = h[2 * t + 1];
    int incl = scanIncl256(p0 + p1, t, wsum);
    s2[t] = incl;
    int ex = incl - p0 - p1;
    ls[2 * t] = ex;           ls[2 * t + 1] = ex + p0;
    lcur[2 * t] = ex;         lcur[2 * t + 1] = ex + p0;
    __syncthreads();
    // global bases (one atomic per non-empty bucket)
    for (int b = t; b < NB; b += 256)
        hb[b] = h[b] ? atomicAdd(&bcur[b], h[b]) : 0;
    __syncthreads();
    // LDS scatter by local rank
#pragma unroll
    for (int e = 0; e < 16; e++) {
        if (bk[e] < 0) continue;
        int pos = atomicAdd(&lcur[bk[e]], 1);
        Qp[pos] = val[e];
        Bq[pos] = (unsigned short)bk[e];
    }
    __syncthreads();
    // linear flush: consecutive j -> same bucket -> adjacent global slots
    int total = s2[255];
    for (int j = t; j < total; j += 256) {
        int bkj = Bq[j];
        int gp = hb[bkj] + (j - ls[bkj]);
        if (gp < PSTRIDE)                  // overflow guard (stat. impossible)
            pairs[(size_t)bkj * PSTRIDE + gp] = Qp[j];
    }
}

// --- per-bucket CSR fill with FUSED counting sort by src>>9 -----------------
// srcs segment built in LDS S[] then flushed linearly (coalesced, R26).
// Sorted Q -> each node's CSR list fills ~ascending in src (convoy).
// R28: all three 256-wide scans are shuffle-based (2 barriers each).
__global__ __launch_bounds__(256) void build_csr(const unsigned int* __restrict__ pairs,
                                                 const int* __restrict__ bcur,
                                                 int n, int NB,
                                                 int* __restrict__ rowptr,
                                                 int* __restrict__ srcs) {
    int b = blockIdx.x, t = threadIdx.x;
    __shared__ int c[512];
    __shared__ int s2[256];
    __shared__ int wsum[4];
    __shared__ int sbase, stot;
    __shared__ unsigned int Q[PSTRIDE];    // 18.4 KB sorted bucket
    __shared__ int S[NPB + PSTRIDE];       // 19.4 KB staged srcs segment
    __shared__ int hist[256];
    __shared__ int hcur[256];
    // ---- global bucket-count scan (for CSR base offset), shuffle scan ----
    int c0 = (2 * t < NB) ? min(bcur[2 * t], PSTRIDE) : 0;
    int c1 = (2 * t + 1 < NB) ? min(bcur[2 * t + 1], PSTRIDE) : 0;
    c[2 * t] = c0; c[2 * t + 1] = c1;
    hist[t] = 0;
    __syncthreads();                       // c[], hist[] visible
    int incl = scanIncl256(c0 + c1, t, wsum);
    s2[t] = incl;
    __syncthreads();
    if (t == 0) {
        int p = b >> 1;
        int ex = s2[p] - (c[2 * p] + c[2 * p + 1]);
        sbase = ex + ((b & 1) ? c[b & ~1] : 0);
        stot = s2[255];
    }
    __syncthreads();
    int d0 = b << 8;
    int nb = min(NPB, n - d0);
    int cnt_b = c[b];
    int csr0 = sbase + d0;   // pairs before + one self-loop per node before
    const unsigned int* pb = pairs + (size_t)b * PSTRIDE;

    // ---- counting sort by src>>9 into Q ----
    for (int j = t; j < cnt_b; j += 256)
        atomicAdd(&hist[(pb[j] & 0xFFFFFFu) >> 9], 1);   // key <= 195
    __syncthreads();
    int hv = hist[t];
    int hincl = scanIncl256(hv, t, wsum);
    hcur[t] = hincl - hv;                 // exclusive base -> cursor
    __syncthreads();
    for (int j = t; j < cnt_b; j += 256) {
        unsigned int p = pb[j];
        int pos = atomicAdd(&hcur[(p & 0xFFFFFFu) >> 9], 1);
        Q[pos] = p;
    }
    __syncthreads();

    // ---- degree count / scan / fill (into LDS S) from sorted Q ----
    __shared__ int deg[NPB];
    __shared__ int cur[NPB];
    deg[t] = (t < nb) ? 1 : 0;   // self-loop
    __syncthreads();
    for (int j = t; j < cnt_b; j += 256)
        atomicAdd(&deg[Q[j] >> 24], 1);
    __syncthreads();
    int v = deg[t];
    int dincl = scanIncl256(v, t, wsum);
    int excl = dincl - v;
    if (t < nb) {
        rowptr[d0 + t] = csr0 + excl;
        S[excl] = d0 + t;             // self-loop at slot 0
        cur[t] = excl + 1;
    }
    __syncthreads();
    // j-round order over sorted Q -> each node's list fills ~ascending in src
    for (int j = t; j < cnt_b; j += 256) {
        unsigned int p = Q[j];
        int off = atomicAdd(&cur[p >> 24], 1);
        S[off] = (int)(p & 0x00FFFFFFu);
    }
    __syncthreads();
    // coalesced flush of the block's whole srcs segment
    int seg = nb + cnt_b;
    for (int j = t; j < seg; j += 256)
        srcs[csr0 + j] = S[j];
    if (b == 0 && t == 0) rowptr[n] = n + stot;
}

// --- tiled node GEMM: 64 nodes x 64 cols per block, 4x4 per thread ----------
// float4-vectorized x staging (R21; a float4 never straddles lim since
// IN_DIM % 4 == 0 and lim is a multiple of IN_DIM).
template <int IN_DIM>
__global__ __launch_bounds__(256) void node_gemm(const float* __restrict__ x,
                                                 const float* __restrict__ W,
                                                 const float* __restrict__ a_src,
                                                 const float* __restrict__ a_dst,
                                                 const float* __restrict__ bias_in,
                                                 float slope_in,
                                                 unsigned short* __restrict__ h16,
                                                 float* __restrict__ al_s,
                                                 float* __restrict__ al_d,
                                                 int n) {
    __shared__ float Ws[IN_DIM * 64];
    __shared__ float xs[IN_DIM][XPAD];
    int t = threadIdx.x;
    int nbase = blockIdx.x * 64;

    for (int idx = t; idx < IN_DIM * 16; idx += 256)
        ((float4*)Ws)[idx] = ((const float4*)W)[idx];
    const float* xb = x + (size_t)nbase * IN_DIM;
    int lim = min(64, n - nbase) * IN_DIM;           // in floats
    constexpr int NV = (64 * IN_DIM) / 4;            // float4 elements
    for (int idx = t; idx < NV; idx += 256) {
        int f0 = idx * 4;
        float4 v = make_float4(0.0f, 0.0f, 0.0f, 0.0f);
        if (f0 < lim) v = ((const float4*)xb)[idx];  // coalesced 16B/lane
        int node = f0 / IN_DIM;
        int k = f0 - node * IN_DIM;
        if (bias_in) {
            v.x += bias_in[k + 0];
            v.y += bias_in[k + 1];
            v.z += bias_in[k + 2];
            v.w += bias_in[k + 3];
            v.x = (v.x >= 0.0f) ? v.x : slope_in * v.x;
            v.y = (v.y >= 0.0f) ? v.y : slope_in * v.y;
            v.z = (v.z >= 0.0f) ? v.z : slope_in * v.z;
            v.w = (v.w >= 0.0f) ? v.w : slope_in * v.w;
        }
        xs[k + 0][node] = v.x;
        xs[k + 1][node] = v.y;
        xs[k + 2][node] = v.z;
        xs[k + 3][node] = v.w;
    }
    __syncthreads();

    int cg = t & 15;    // col group: cols 4cg..4cg+3
    int ng = t >> 4;    // node group: nodes 4ng..4ng+3
    float acc[4][4] = {};
#pragma unroll 8
    for (int k = 0; k < IN_DIM; k++) {
        float4 xv = *(const float4*)&xs[k][ng * 4];
        float4 wv = *(const float4*)&Ws[k * 64 + cg * 4];
        float xa[4] = {xv.x, xv.y, xv.z, xv.w};
        float wa[4] = {wv.x, wv.y, wv.z, wv.w};
#pragma unroll
        for (int i = 0; i < 4; i++)
#pragma unroll
            for (int j = 0; j < 4; j++)
                acc[i][j] += xa[i] * wa[j];
    }

    float4 as4 = *(const float4*)(a_src + cg * 4);
    float4 ad4 = *(const float4*)(a_dst + cg * 4);
#pragma unroll
    for (int i = 0; i < 4; i++) {
        int node = nbase + ng * 4 + i;
        if (node < n) {
            uint2 p;
            p.x = f2bf(acc[i][0]) | (f2bf(acc[i][1]) << 16);
            p.y = f2bf(acc[i][2]) | (f2bf(acc[i][3]) << 16);
            *(uint2*)(h16 + (size_t)node * 64 + cg * 4) = p;
        }
        float vs = acc[i][0] * as4.x + acc[i][1] * as4.y +
                   acc[i][2] * as4.z + acc[i][3] * as4.w;
        float vd = acc[i][0] * ad4.x + acc[i][1] * ad4.y +
                   acc[i][2] * ad4.z + acc[i][3] * ad4.w;
#pragma unroll
        for (int o = 8; o; o >>= 1) {
            vs += __shfl_xor(vs, o);
            vd += __shfl_xor(vd, o);
        }
        if (cg == 0 && node < n) { al_s[node] = vs; al_d[node] = vd; }
    }
}

// --- single-pass aggregate (R17 proven body, BYTE-IDENTICAL): ---------------
// 8 lanes/node, depth-4 prefetch. 53.4us / 32 VGPR / no spill.
// out[node] = (sum_j exp(e_j)*h[src_j]) / (sum_j exp(e_j) + 1e-16)
__device__ __forceinline__ void bf8_fma(float* acc, uint4 q, float w) {
    acc[0] += w * __uint_as_float(q.x << 16);
    acc[1] += w * __uint_as_float(q.x & 0xFFFF0000u);
    acc[2] += w * __uint_as_float(q.y << 16);
    acc[3] += w * __uint_as_float(q.y & 0xFFFF0000u);
    acc[4] += w * __uint_as_float(q.z << 16);
    acc[5] += w * __uint_as_float(q.z & 0xFFFF0000u);
    acc[6] += w * __uint_as_float(q.w << 16);
    acc[7] += w * __uint_as_float(q.w & 0xFFFF0000u);
}

__global__ __launch_bounds__(256) void gat_aggregate(const int* __restrict__ rowptr,
                                                     const int* __restrict__ srcs,
                                                     const float* __restrict__ als,
                                                     const float* __restrict__ ald,
                                                     const unsigned short* __restrict__ h16,
                                                     float* __restrict__ hout,
                                                     int n) {
    int t = threadIdx.x;
    int sub = t >> 3, lane = t & 7;       // 32 nodes/block, 8 lanes/node
    int node = blockIdx.x * 32 + sub;
    if (node >= n) return;
    int beg = rowptr[node], end = rowptr[node + 1];
    float aldv = ald[node];
    const unsigned short* hb = h16 + lane * 8;

    float acc[8] = {};
    float sm = 0.0f;
    int j = beg;
    if (j + 4 <= end) {
        int s0 = srcs[j], s1 = srcs[j + 1], s2 = srcs[j + 2], s3 = srcs[j + 3];
        for (; j + 8 <= end; j += 4) {
            // prefetch next quad's indices: breaks srcs->gather serial chain
            int n0 = srcs[j + 4], n1 = srcs[j + 5];
            int n2 = srcs[j + 6], n3 = srcs[j + 7];
            float e0 = als[s0] + aldv, e1 = als[s1] + aldv;
            float e2 = als[s2] + aldv, e3 = als[s3] + aldv;
            uint4 q0 = *(const uint4*)(hb + (size_t)s0 * 64);
            uint4 q1 = *(const uint4*)(hb + (size_t)s1 * 64);
            uint4 q2 = *(const uint4*)(hb + (size_t)s2 * 64);
            uint4 q3 = *(const uint4*)(hb + (size_t)s3 * 64);
            e0 = (e0 >= 0.0f) ? e0 : 0.2f * e0;
            e1 = (e1 >= 0.0f) ? e1 : 0.2f * e1;
            e2 = (e2 >= 0.0f) ? e2 : 0.2f * e2;
            e3 = (e3 >= 0.0f) ? e3 : 0.2f * e3;
            float w0 = __expf(e0), w1 = __expf(e1);
            float w2 = __expf(e2), w3 = __expf(e3);
            sm += (w0 + w1) + (w2 + w3);
            bf8_fma(acc, q0, w0);
            bf8_fma(acc, q1, w1);
            bf8_fma(acc, q2, w2);
            bf8_fma(acc, q3, w3);
            s0 = n0; s1 = n1; s2 = n2; s3 = n3;
        }
        // final full quad (s0..s3 already loaded)
        {
            float e0 = als[s0] + aldv, e1 = als[s1] + aldv;
            float e2 = als[s2] + aldv, e3 = als[s3] + aldv;
            uint4 q0 = *(const uint4*)(hb + (size_t)s0 * 64);
            uint4 q1 = *(const uint4*)(hb + (size_t)s1 * 64);
            uint4 q2 = *(const uint4*)(hb + (size_t)s2 * 64);
            uint4 q3 = *(const uint4*)(hb + (size_t)s3 * 64);
            e0 = (e0 >= 0.0f) ? e0 : 0.2f * e0;
            e1 = (e1 >= 0.0f) ? e1 : 0.2f * e1;
            e2 = (e2 >= 0.0f) ? e2 : 0.2f * e2;
            e3 = (e3 >= 0.0f) ? e3 : 0.2f * e3;
            float w0 = __expf(e0), w1 = __expf(e1);
            float w2 = __expf(e2), w3 = __expf(e3);
            sm += (w0 + w1) + (w2 + w3);
            bf8_fma(acc, q0, w0);
            bf8_fma(acc, q1, w1);
            bf8_fma(acc, q2, w2);
            bf8_fma(acc, q3, w3);
            j += 4;
        }
    }
    for (; j < end; j++) {
        int s = srcs[j];
        float e = als[s] + aldv;
        e = (e >= 0.0f) ? e : 0.2f * e;
        float w = __expf(e);
        uint4 q = *(const uint4*)(hb + (size_t)s * 64);
        sm += w;
        bf8_fma(acc, q, w);
    }

    float inv = 1.0f / (sm + 1e-16f);
    float4 o0 = make_float4(acc[0] * inv, acc[1] * inv, acc[2] * inv, acc[3] * inv);
    float4 o1 = make_float4(acc[4] * inv, acc[5] * inv, acc[6] * inv, acc[7] * inv);
    float* op = hout + (size_t)node * 64 + lane * 8;
    *(float4*)op = o0;
    *(float4*)(op + 4) = o1;
}

// --- fused pool + FC: one block per graph, float4 hout reads ----------------
__global__ __launch_bounds__(256) void pool_fc(const float* __restrict__ hout,
                                               const float* __restrict__ b2,
                                               const int* __restrict__ batch,
                                               const float* __restrict__ fcW,
                                               const float* __restrict__ fcb,
                                               float* __restrict__ out, int n) {
    int g = blockIdx.x;
    int t = threadIdx.x;
    __shared__ int sLo, sHi;
    __shared__ float red[16][64];
    if (t == 0) {
        int lo = 0, hi = n;
        while (lo < hi) { int m = (lo + hi) >> 1; if (batch[m] < g) lo = m + 1; else hi = m; }
        sLo = lo;
    } else if (t == 64) {
        int lo = 0, hi = n;
        while (lo < hi) { int m = (lo + hi) >> 1; if (batch[m] < g + 1) lo = m + 1; else hi = m; }
        sHi = lo;
    }
    __syncthreads();
    int lo = sLo, hi = sHi;
    int q = t & 15;     // float4 index within 64-float row
    int r = t >> 4;     // node offset (stride 16)
    float4 a4 = make_float4(0.0f, 0.0f, 0.0f, 0.0f);
    for (int node = lo + r; node < hi; node += 16) {
        float4 v = *(const float4*)(hout + (size_t)node * 64 + q * 4);
        a4.x += v.x; a4.y += v.y; a4.z += v.z; a4.w += v.w;
    }
    *(float4*)&red[r][q * 4] = a4;
    __syncthreads();
    if (t < 64) {
        float c = (float)(hi - lo);
        float s = 0.0f;
#pragma unroll
        for (int i = 0; i < 16; i++) s += red[i][t];
        s += c * b2[t];
        float cd = (c > 1.0f) ? c : 1.0f;
        float p = s / cd;
        float s0 = p * fcW[t * 2 + 0];
        float s1 = p * fcW[t * 2 + 1];
#pragma unroll
        for (int o = 32; o; o >>= 1) {
            s0 += __shfl_xor(s0, o);
            s1 += __shfl_xor(s1, o);
        }
        if (t == 0) {
            out[g * 2 + 0] = s0 + fcb[0];
            out[g * 2 + 1] = s1 + fcb[1];
        }
    }
}

extern "C" void kernel_launch(void* const* d_in, const int* in_sizes, int n_in,
                              void* d_out, int out_size, void* d_ws, size_t ws_size,
                              hipStream_t stream) {
    const float* x    = (const float*)d_in[0];
    const int*   ei   = (const int*)d_in[1];
    const int*   batch= (const int*)d_in[2];
    const float* W1   = (const float*)d_in[3];
    const float* as1  = (const float*)d_in[4];
    const float* ad1  = (const float*)d_in[5];
    const float* b1   = (const float*)d_in[6];
    const float* W2   = (const float*)d_in[7];
    const float* as2  = (const float*)d_in[8];
    const float* ad2  = (const float*)d_in[9];
    const float* b2   = (const float*)d_in[10];
    const float* fcW  = (const float*)d_in[11];
    const float* fcb  = (const float*)d_in[12];
    float* out = (float*)d_out;

    const int N = in_sizes[2];       // 100000
    const int E = in_sizes[1] / 2;   // 1600000
    const int G = out_size / 2;      // 256
    const int tot = E + N;
    const int NB = (N + NPB - 1) / NPB;   // 391 buckets

    // ws layout (~46 MiB): pairs ALIASES bufO (disjoint lifetimes:
    // pairs die at build_csr; bufO first written by aggregate layer 1).
    float* ws     = (float*)d_ws;
    float* bufO   = ws;                                  // N*64 fp32  25.6 MB
    unsigned int* pairs  = (unsigned int*)bufO;          // alias      7.2 MB
    float* als    = bufO + (size_t)N * 64;               // N          0.4 MB
    float* ald    = als + N;                             // N          0.4 MB
    int*   rowptr = (int*)(ald + N);                     // N+1        0.4 MB
    int*   srcs   = rowptr + N + 1;                      // tot        6.8 MB
    int*   bcur   = srcs + tot;                          // NB
    unsigned short* bufH16 = (unsigned short*)(bcur + NB);  // N*64   12.8 MB

    dim3 b256(256);
    int gPart = (E + EPB - 1) / EPB;
    int gGemm = (N + 63) / 64;
    int gAgg  = (N + 31) / 32;

    // ---- CSR build: memset cursors + partition + fused sort/fill -----------
    hipMemsetAsync(bcur, 0, (size_t)NB * sizeof(int), stream);
    partition<<<gPart, b256, 0, stream>>>(ei, E, NB, bcur, pairs);
    build_csr<<<NB, b256, 0, stream>>>(pairs, bcur, N, NB, rowptr, srcs);

    // ---- layer 1 ----
    node_gemm<72><<<gGemm, b256, 0, stream>>>(x, W1, as1, ad1, nullptr, 0.0f,
                                              bufH16, als, ald, N);
    gat_aggregate<<<gAgg, b256, 0, stream>>>(rowptr, srcs, als, ald, bufH16, bufO, N);

    // ---- layer 2 (input = leaky(bufO + b1, 0.01)) ----
    node_gemm<64><<<gGemm, b256, 0, stream>>>(bufO, W2, as2, ad2, b1, 0.01f,
                                              bufH16, als, ald, N);
    gat_aggregate<<<gAgg, b256, 0, stream>>>(rowptr, srcs, als, ald, bufH16, bufO, N);

    // ---- fused pool + fc ----
    pool_fc<<<G, b256, 0, stream>>>(bufO, b2, batch, fcW, fcb, out, N);
}

// Round 18
// 287.766 us; speedup vs baseline: 1.1136x; 1.0233x over previous
//
#include <hip/hip_runtime.h>
#include <hip/hip_bf16.h>
#include <math.h>

// ---------------------------------------------------------------------------
// GAT: 2x GATConv(heads=1) + global mean pool + FC(64->2)
// R29 = R28 (best, 294.5us) + partition FUSED into gemm1's dispatch.
//   partition (391 blk) and node_gemm<72> (1563 blk) are data-independent;
//   serial on one stream they cost ~9 + ~15us + a launch gap. One fused
//   dispatch (blockIdx < gPart -> partition body, else gemm body; shared
//   memory UNION 38KB -> same 4 blk/CU occupancy as standalone gemm)
//   co-schedules them: dur ~ max + eps, one launch gone. Branch is
//   block-uniform so divergent barriers are safe. Bodies byte-identical
//   to R28. build_csr still follows (stream order preserves its dep).
//   Aggregate / node_gemm<64> / pool_fc BYTE-IDENTICAL to R28.
// ---------------------------------------------------------------------------

#define NPB 256          // nodes per bucket
#define EPB 4096         // edges per partition block (256 thr x 16)
#define PSTRIDE 4608     // slots per bucket (lambda=4092, +8 sigma)
#define XPAD 68          // xs leading-dim pad: 8-way banks, 16B-aligned rows

__device__ __forceinline__ unsigned int f2bf(float v) {
    unsigned int b = __float_as_uint(v);
    b += 0x7FFFu + ((b >> 16) & 1u);   // round-to-nearest-even
    return b >> 16;
}

// inclusive scan of one value per thread across 256 threads: wave64 shuffle
// scan + cross-wave combine via 4-entry LDS. Exactly 2 __syncthreads().
__device__ __forceinline__ int scanIncl256(int v, int t, int* wsum) {
    int lane = t & 63, wv = t >> 6;
#pragma unroll
    for (int o = 1; o < 64; o <<= 1) {
        int u = __shfl_up(v, o);
        if (lane >= o) v += u;
    }
    if (lane == 63) wsum[wv] = v;
    __syncthreads();
    int base = 0;
#pragma unroll
    for (int i = 0; i < 3; i++) base += (i < wv) ? wsum[i] : 0;
    __syncthreads();                     // guards wsum reuse by next call
    return v + base;
}

// --- fused partition + gemm1 shared-memory union ----------------------------
struct PartSh {
    int h[512];                 // per-bucket counts
    int ls[512];                // exclusive local starts
    int lcur[512];              // scatter cursors
    int hb[512];                // global bases
    int s2[256];
    int wsum[4];
    unsigned int Qp[EPB];       // 16 KB staged vals
    unsigned short Bq[EPB];     // 8 KB bucket ids
};                              // ~33.8 KB
struct GemmSh {
    float Ws[72 * 64];          // 18 KB
    float xs[72][XPAD];         // 19.1 KB
};                              // ~37.1 KB
union FusedSh { PartSh p; GemmSh g; };

// --- fused kernel: blocks [0,gPart) partition edges; rest do gemm layer 1 ---
__global__ __launch_bounds__(256) void part_gemm(const int* __restrict__ ei,
                                                 int E, int NB,
                                                 int* __restrict__ bcur,
                                                 unsigned int* __restrict__ pairs,
                                                 int gPart,
                                                 const float* __restrict__ x,
                                                 const float* __restrict__ W,
                                                 const float* __restrict__ a_src,
                                                 const float* __restrict__ a_dst,
                                                 unsigned short* __restrict__ h16,
                                                 float* __restrict__ al_s,
                                                 float* __restrict__ al_d,
                                                 int n) {
    __shared__ FusedSh sh;
    int t = threadIdx.x;
    if ((int)blockIdx.x < gPart) {
        // ================= partition body (R28, byte-equivalent) ===========
        int* h = sh.p.h;
        int* ls = sh.p.ls;
        int* lcur = sh.p.lcur;
        int* hb = sh.p.hb;
        int* s2 = sh.p.s2;
        for (int i = t; i < 512; i += 256) h[i] = 0;
        __syncthreads();
        int i0 = blockIdx.x * EPB;
        unsigned int val[16];
        int bk[16];
        const int4* s4p = (const int4*)(ei);
        const int4* d4p = (const int4*)(ei + E);
#pragma unroll
        for (int k = 0; k < 4; k++) {
            int vbase = (i0 >> 2) + k * 256 + t;   // int4 index
            int i = vbase << 2;
            if (i < E) {                           // E%4==0 -> whole int4 valid
                int4 s4 = s4p[vbase];
                int4 d4 = d4p[vbase];
                int ss[4] = {s4.x, s4.y, s4.z, s4.w};
                int dd[4] = {d4.x, d4.y, d4.z, d4.w};
#pragma unroll
                for (int j = 0; j < 4; j++) {
                    int e = k * 4 + j;
                    bk[e] = dd[j] >> 8;
                    val[e] = (unsigned)ss[j] | ((unsigned)(dd[j] & 255) << 24);
                    atomicAdd(&h[bk[e]], 1);
                }
            } else {
#pragma unroll
                for (int j = 0; j < 4; j++) bk[k * 4 + j] = -1;
            }
        }
        __syncthreads();
        // exclusive scan of h[0..511] via pairwise shuffle scan (2 barriers)
        int p0 = h[2 * t], p1 = h[2 * t + 1];
        int incl = scanIncl256(p0 + p1, t, sh.p.wsum);
        s2[t] = incl;
        int ex = incl - p0 - p1;
        ls[2 * t] = ex;           ls[2 * t + 1] = ex + p0;
        lcur[2 * t] = ex;         lcur[2 * t + 1] = ex + p0;
        __syncthreads();
        // global bases (one atomic per non-empty bucket)
        for (int b = t; b < NB; b += 256)
            hb[b] = h[b] ? atomicAdd(&bcur[b], h[b]) : 0;
        __syncthreads();
        // LDS scatter by local rank
#pragma unroll
        for (int e = 0; e < 16; e++) {
            if (bk[e] < 0) continue;
            int pos = atomicAdd(&lcur[bk[e]], 1);
            sh.p.Qp[pos] = val[e];
            sh.p.Bq[pos] = (unsigned short)bk[e];
        }
        __syncthreads();
        // linear flush: consecutive j -> same bucket -> adjacent global slots
        int total = s2[255];
        for (int j = t; j < total; j += 256) {
            int bkj = sh.p.Bq[j];
            int gp = hb[bkj] + (j - ls[bkj]);
            if (gp < PSTRIDE)              // overflow guard (stat. impossible)
                pairs[(size_t)bkj * PSTRIDE + gp] = sh.p.Qp[j];
        }
    } else {
        // ================= gemm layer-1 body (R21, IN_DIM=72) ==============
        constexpr int IN_DIM = 72;
        float* Ws = sh.g.Ws;
        int nbase = ((int)blockIdx.x - gPart) * 64;

        for (int idx = t; idx < IN_DIM * 16; idx += 256)
            ((float4*)Ws)[idx] = ((const float4*)W)[idx];
        const float* xb = x + (size_t)nbase * IN_DIM;
        int lim = min(64, n - nbase) * IN_DIM;           // in floats
        constexpr int NV = (64 * IN_DIM) / 4;            // float4 elements
        for (int idx = t; idx < NV; idx += 256) {
            int f0 = idx * 4;
            float4 v = make_float4(0.0f, 0.0f, 0.0f, 0.0f);
            if (f0 < lim) v = ((const float4*)xb)[idx];  // coalesced 16B/lane
            int node = f0 / IN_DIM;
            int k = f0 - node * IN_DIM;
            sh.g.xs[k + 0][node] = v.x;
            sh.g.xs[k + 1][node] = v.y;
            sh.g.xs[k + 2][node] = v.z;
            sh.g.xs[k + 3][node] = v.w;
        }
        __syncthreads();

        int cg = t & 15;    // col group: cols 4cg..4cg+3
        int ng = t >> 4;    // node group: nodes 4ng..4ng+3
        float acc[4][4] = {};
#pragma unroll 8
        for (int k = 0; k < IN_DIM; k++) {
            float4 xv = *(const float4*)&sh.g.xs[k][ng * 4];
            float4 wv = *(const float4*)&Ws[k * 64 + cg * 4];
            float xa[4] = {xv.x, xv.y, xv.z, xv.w};
            float wa[4] = {wv.x, wv.y, wv.z, wv.w};
#pragma unroll
            for (int i = 0; i < 4; i++)
#pragma unroll
                for (int j = 0; j < 4; j++)
                    acc[i][j] += xa[i] * wa[j];
        }

        float4 as4 = *(const float4*)(a_src + cg * 4);
        float4 ad4 = *(const float4*)(a_dst + cg * 4);
#pragma unroll
        for (int i = 0; i < 4; i++) {
            int node = nbase + ng * 4 + i;
            if (node < n) {
                uint2 p;
                p.x = f2bf(acc[i][0]) | (f2bf(acc[i][1]) << 16);
                p.y = f2bf(acc[i][2]) | (f2bf(acc[i][3]) << 16);
                *(uint2*)(h16 + (size_t)node * 64 + cg * 4) = p;
            }
            float vs = acc[i][0] * as4.x + acc[i][1] * as4.y +
                       acc[i][2] * as4.z + acc[i][3] * as4.w;
            float vd = acc[i][0] * ad4.x + acc[i][1] * ad4.y +
                       acc[i][2] * ad4.z + acc[i][3] * ad4.w;
#pragma unroll
            for (int o = 8; o; o >>= 1) {
                vs += __shfl_xor(vs, o);
                vd += __shfl_xor(vd, o);
            }
            if (cg == 0 && node < n) { al_s[node] = vs; al_d[node] = vd; }
        }
    }
}

// --- per-bucket CSR fill with FUSED counting sort by src>>9 -----------------
// srcs segment built in LDS S[] then flushed linearly (coalesced, R26).
// Sorted Q -> each node's CSR list fills ~ascending in src (convoy).
// Shuffle-based scans (R28, 2 barriers each).
__global__ __launch_bounds__(256) void build_csr(const unsigned int* __restrict__ pairs,
                                                 const int* __restrict__ bcur,
                                                 int n, int NB,
                                                 int* __restrict__ rowptr,
                                                 int* __restrict__ srcs) {
    int b = blockIdx.x, t = threadIdx.x;
    __shared__ int c[512];
    __shared__ int s2[256];
    __shared__ int wsum[4];
    __shared__ int sbase, stot;
    __shared__ unsigned int Q[PSTRIDE];    // 18.4 KB sorted bucket
    __shared__ int S[NPB + PSTRIDE];       // 19.4 KB staged srcs segment
    __shared__ int hist[256];
    __shared__ int hcur[256];
    // ---- global bucket-count scan (for CSR base offset), shuffle scan ----
    int c0 = (2 * t < NB) ? min(bcur[2 * t], PSTRIDE) : 0;
    int c1 = (2 * t + 1 < NB) ? min(bcur[2 * t + 1], PSTRIDE) : 0;
    c[2 * t] = c0; c[2 * t + 1] = c1;
    hist[t] = 0;
    __syncthreads();                       // c[], hist[] visible
    int incl = scanIncl256(c0 + c1, t, wsum);
    s2[t] = incl;
    __syncthreads();
    if (t == 0) {
        int p = b >> 1;
        int ex = s2[p] - (c[2 * p] + c[2 * p + 1]);
        sbase = ex + ((b & 1) ? c[b & ~1] : 0);
        stot = s2[255];
    }
    __syncthreads();
    int d0 = b << 8;
    int nb = min(NPB, n - d0);
    int cnt_b = c[b];
    int csr0 = sbase + d0;   // pairs before + one self-loop per node before
    const unsigned int* pb = pairs + (size_t)b * PSTRIDE;

    // ---- counting sort by src>>9 into Q ----
    for (int j = t; j < cnt_b; j += 256)
        atomicAdd(&hist[(pb[j] & 0xFFFFFFu) >> 9], 1);   // key <= 195
    __syncthreads();
    int hv = hist[t];
    int hincl = scanIncl256(hv, t, wsum);
    hcur[t] = hincl - hv;                 // exclusive base -> cursor
    __syncthreads();
    for (int j = t; j < cnt_b; j += 256) {
        unsigned int p = pb[j];
        int pos = atomicAdd(&hcur[(p & 0xFFFFFFu) >> 9], 1);
        Q[pos] = p;
    }
    __syncthreads();

    // ---- degree count / scan / fill (into LDS S) from sorted Q ----
    __shared__ int deg[NPB];
    __shared__ int cur[NPB];
    deg[t] = (t < nb) ? 1 : 0;   // self-loop
    __syncthreads();
    for (int j = t; j < cnt_b; j += 256)
        atomicAdd(&deg[Q[j] >> 24], 1);
    __syncthreads();
    int v = deg[t];
    int dincl = scanIncl256(v, t, wsum);
    int excl = dincl - v;
    if (t < nb) {
        rowptr[d0 + t] = csr0 + excl;
        S[excl] = d0 + t;             // self-loop at slot 0
        cur[t] = excl + 1;
    }
    __syncthreads();
    // j-round order over sorted Q -> each node's list fills ~ascending in src
    for (int j = t; j < cnt_b; j += 256) {
        unsigned int p = Q[j];
        int off = atomicAdd(&cur[p >> 24], 1);
        S[off] = (int)(p & 0x00FFFFFFu);
    }
    __syncthreads();
    // coalesced flush of the block's whole srcs segment
    int seg = nb + cnt_b;
    for (int j = t; j < seg; j += 256)
        srcs[csr0 + j] = S[j];
    if (b == 0 && t == 0) rowptr[n] = n + stot;
}

// --- tiled node GEMM (layer 2): 64 nodes x 64 cols, float4 staging ----------
template <int IN_DIM>
__global__ __launch_bounds__(256) void node_gemm(const float* __restrict__ x,
                                                 const float* __restrict__ W,
                                                 const float* __restrict__ a_src,
                                                 const float* __restrict__ a_dst,
                                                 const float* __restrict__ bias_in,
                                                 float slope_in,
                                                 unsigned short* __restrict__ h16,
                                                 float* __restrict__ al_s,
                                                 float* __restrict__ al_d,
                                                 int n) {
    __shared__ float Ws[IN_DIM * 64];
    __shared__ float xs[IN_DIM][XPAD];
    int t = threadIdx.x;
    int nbase = blockIdx.x * 64;

    for (int idx = t; idx < IN_DIM * 16; idx += 256)
        ((float4*)Ws)[idx] = ((const float4*)W)[idx];
    const float* xb = x + (size_t)nbase * IN_DIM;
    int lim = min(64, n - nbase) * IN_DIM;           // in floats
    constexpr int NV = (64 * IN_DIM) / 4;            // float4 elements
    for (int idx = t; idx < NV; idx += 256) {
        int f0 = idx * 4;
        float4 v = make_float4(0.0f, 0.0f, 0.0f, 0.0f);
        if (f0 < lim) v = ((const float4*)xb)[idx];  // coalesced 16B/lane
        int node = f0 / IN_DIM;
        int k = f0 - node * IN_DIM;
        if (bias_in) {
            v.x += bias_in[k + 0];
            v.y += bias_in[k + 1];
            v.z += bias_in[k + 2];
            v.w += bias_in[k + 3];
            v.x = (v.x >= 0.0f) ? v.x : slope_in * v.x;
            v.y = (v.y >= 0.0f) ? v.y : slope_in * v.y;
            v.z = (v.z >= 0.0f) ? v.z : slope_in * v.z;
            v.w = (v.w >= 0.0f) ? v.w : slope_in * v.w;
        }
        xs[k + 0][node] = v.x;
        xs[k + 1][node] = v.y;
        xs[k + 2][node] = v.z;
        xs[k + 3][node] = v.w;
    }
    __syncthreads();

    int cg = t & 15;    // col group: cols 4cg..4cg+3
    int ng = t >> 4;    // node group: nodes 4ng..4ng+3
    float acc[4][4] = {};
#pragma unroll 8
    for (int k = 0; k < IN_DIM; k++) {
        float4 xv = *(const float4*)&xs[k][ng * 4];
        float4 wv = *(const float4*)&Ws[k * 64 + cg * 4];
        float xa[4] = {xv.x, xv.y, xv.z, xv.w};
        float wa[4] = {wv.x, wv.y, wv.z, wv.w};
#pragma unroll
        for (int i = 0; i < 4; i++)
#pragma unroll
            for (int j = 0; j < 4; j++)
                acc[i][j] += xa[i] * wa[j];
    }

    float4 as4 = *(const float4*)(a_src + cg * 4);
    float4 ad4 = *(const float4*)(a_dst + cg * 4);
#pragma unroll
    for (int i = 0; i < 4; i++) {
        int node = nbase + ng * 4 + i;
        if (node < n) {
            uint2 p;
            p.x = f2bf(acc[i][0]) | (f2bf(acc[i][1]) << 16);
            p.y = f2bf(acc[i][2]) | (f2bf(acc[i][3]) << 16);
            *(uint2*)(h16 + (size_t)node * 64 + cg * 4) = p;
        }
        float vs = acc[i][0] * as4.x + acc[i][1] * as4.y +
                   acc[i][2] * as4.z + acc[i][3] * as4.w;
        float vd = acc[i][0] * ad4.x + acc[i][1] * ad4.y +
                   acc[i][2] * ad4.z + acc[i][3] * ad4.w;
#pragma unroll
        for (int o = 8; o; o >>= 1) {
            vs += __shfl_xor(vs, o);
            vd += __shfl_xor(vd, o);
        }
        if (cg == 0 && node < n) { al_s[node] = vs; al_d[node] = vd; }
    }
}

// --- single-pass aggregate (R17 proven body, BYTE-IDENTICAL): ---------------
// 8 lanes/node, depth-4 prefetch. 53.4us / 32 VGPR / no spill.
// out[node] = (sum_j exp(e_j)*h[src_j]) / (sum_j exp(e_j) + 1e-16)
__device__ __forceinline__ void bf8_fma(float* acc, uint4 q, float w) {
    acc[0] += w * __uint_as_float(q.x << 16);
    acc[1] += w * __uint_as_float(q.x & 0xFFFF0000u);
    acc[2] += w * __uint_as_float(q.y << 16);
    acc[3] += w * __uint_as_float(q.y & 0xFFFF0000u);
    acc[4] += w * __uint_as_float(q.z << 16);
    acc[5] += w * __uint_as_float(q.z & 0xFFFF0000u);
    acc[6] += w * __uint_as_float(q.w << 16);
    acc[7] += w * __uint_as_float(q.w & 0xFFFF0000u);
}

__global__ __launch_bounds__(256) void gat_aggregate(const int* __restrict__ rowptr,
                                                     const int* __restrict__ srcs,
                                                     const float* __restrict__ als,
                                                     const float* __restrict__ ald,
                                                     const unsigned short* __restrict__ h16,
                                                     float* __restrict__ hout,
                                                     int n) {
    int t = threadIdx.x;
    int sub = t >> 3, lane = t & 7;       // 32 nodes/block, 8 lanes/node
    int node = blockIdx.x * 32 + sub;
    if (node >= n) return;
    int beg = rowptr[node], end = rowptr[node + 1];
    float aldv = ald[node];
    const unsigned short* hb = h16 + lane * 8;

    float acc[8] = {};
    float sm = 0.0f;
    int j = beg;
    if (j + 4 <= end) {
        int s0 = srcs[j], s1 = srcs[j + 1], s2 = srcs[j + 2], s3 = srcs[j + 3];
        for (; j + 8 <= end; j += 4) {
            // prefetch next quad's indices: breaks srcs->gather serial chain
            int n0 = srcs[j + 4], n1 = srcs[j + 5];
            int n2 = srcs[j + 6], n3 = srcs[j + 7];
            float e0 = als[s0] + aldv, e1 = als[s1] + aldv;
            float e2 = als[s2] + aldv, e3 = als[s3] + aldv;
            uint4 q0 = *(const uint4*)(hb + (size_t)s0 * 64);
            uint4 q1 = *(const uint4*)(hb + (size_t)s1 * 64);
            uint4 q2 = *(const uint4*)(hb + (size_t)s2 * 64);
            uint4 q3 = *(const uint4*)(hb + (size_t)s3 * 64);
            e0 = (e0 >= 0.0f) ? e0 : 0.2f * e0;
            e1 = (e1 >= 0.0f) ? e1 : 0.2f * e1;
            e2 = (e2 >= 0.0f) ? e2 : 0.2f * e2;
            e3 = (e3 >= 0.0f) ? e3 : 0.2f * e3;
            float w0 = __expf(e0), w1 = __expf(e1);
            float w2 = __expf(e2), w3 = __expf(e3);
            sm += (w0 + w1) + (w2 + w3);
            bf8_fma(acc, q0, w0);
            bf8_fma(acc, q1, w1);
            bf8_fma(acc, q2, w2);
            bf8_fma(acc, q3, w3);
            s0 = n0; s1 = n1; s2 = n2; s3 = n3;
        }
        // final full quad (s0..s3 already loaded)
        {
            float e0 = als[s0] + aldv, e1 = als[s1] + aldv;
            float e2 = als[s2] + aldv, e3 = als[s3] + aldv;
            uint4 q0 = *(const uint4*)(hb + (size_t)s0 * 64);
            uint4 q1 = *(const uint4*)(hb + (size_t)s1 * 64);
            uint4 q2 = *(const uint4*)(hb + (size_t)s2 * 64);
            uint4 q3 = *(const uint4*)(hb + (size_t)s3 * 64);
            e0 = (e0 >= 0.0f) ? e0 : 0.2f * e0;
            e1 = (e1 >= 0.0f) ? e1 : 0.2f * e1;
            e2 = (e2 >= 0.0f) ? e2 : 0.2f * e2;
            e3 = (e3 >= 0.0f) ? e3 : 0.2f * e3;
            float w0 = __expf(e0), w1 = __expf(e1);
            float w2 = __expf(e2), w3 = __expf(e3);
            sm += (w0 + w1) + (w2 + w3);
            bf8_fma(acc, q0, w0);
            bf8_fma(acc, q1, w1);
            bf8_fma(acc, q2, w2);
            bf8_fma(acc, q3, w3);
            j += 4;
        }
    }
    for (; j < end; j++) {
        int s = srcs[j];
        float e = als[s] + aldv;
        e = (e >= 0.0f) ? e : 0.2f * e;
        float w = __expf(e);
        uint4 q = *(const uint4*)(hb + (size_t)s * 64);
        sm += w;
        bf8_fma(acc, q, w);
    }

    float inv = 1.0f / (sm + 1e-16f);
    float4 o0 = make_float4(acc[0] * inv, acc[1] * inv, acc[2] * inv, acc[3] * inv);
    float4 o1 = make_float4(acc[4] * inv, acc[5] * inv, acc[6] * inv, acc[7] * inv);
    float* op = hout + (size_t)node * 64 + lane * 8;
    *(float4*)op = o0;
    *(float4*)(op + 4) = o1;
}

// --- fused pool + FC: one block per graph, float4 hout reads ----------------
__global__ __launch_bounds__(256) void pool_fc(const float* __restrict__ hout,
                                               const float* __restrict__ b2,
                                               const int* __restrict__ batch,
                                               const float* __restrict__ fcW,
                                               const float* __restrict__ fcb,
                                               float* __restrict__ out, int n) {
    int g = blockIdx.x;
    int t = threadIdx.x;
    __shared__ int sLo, sHi;
    __shared__ float red[16][64];
    if (t == 0) {
        int lo = 0, hi = n;
        while (lo < hi) { int m = (lo + hi) >> 1; if (batch[m] < g) lo = m + 1; else hi = m; }
        sLo = lo;
    } else if (t == 64) {
        int lo = 0, hi = n;
        while (lo < hi) { int m = (lo + hi) >> 1; if (batch[m] < g + 1) lo = m + 1; else hi = m; }
        sHi = lo;
    }
    __syncthreads();
    int lo = sLo, hi = sHi;
    int q = t & 15;     // float4 index within 64-float row
    int r = t >> 4;     // node offset (stride 16)
    float4 a4 = make_float4(0.0f, 0.0f, 0.0f, 0.0f);
    for (int node = lo + r; node < hi; node += 16) {
        float4 v = *(const float4*)(hout + (size_t)node * 64 + q * 4);
        a4.x += v.x; a4.y += v.y; a4.z += v.z; a4.w += v.w;
    }
    *(float4*)&red[r][q * 4] = a4;
    __syncthreads();
    if (t < 64) {
        float c = (float)(hi - lo);
        float s = 0.0f;
#pragma unroll
        for (int i = 0; i < 16; i++) s += red[i][t];
        s += c * b2[t];
        float cd = (c > 1.0f) ? c : 1.0f;
        float p = s / cd;
        float s0 = p * fcW[t * 2 + 0];
        float s1 = p * fcW[t * 2 + 1];
#pragma unroll
        for (int o = 32; o; o >>= 1) {
            s0 += __shfl_xor(s0, o);
            s1 += __shfl_xor(s1, o);
        }
        if (t == 0) {
            out[g * 2 + 0] = s0 + fcb[0];
            out[g * 2 + 1] = s1 + fcb[1];
        }
    }
}

extern "C" void kernel_launch(void* const* d_in, const int* in_sizes, int n_in,
                              void* d_out, int out_size, void* d_ws, size_t ws_size,
                              hipStream_t stream) {
    const float* x    = (const float*)d_in[0];
    const int*   ei   = (const int*)d_in[1];
    const int*   batch= (const int*)d_in[2];
    const float* W1   = (const float*)d_in[3];
    const float* as1  = (const float*)d_in[4];
    const float* ad1  = (const float*)d_in[5];
    const float* b1   = (const float*)d_in[6];
    const float* W2   = (const float*)d_in[7];
    const float* as2  = (const float*)d_in[8];
    const float* ad2  = (const float*)d_in[9];
    const float* b2   = (const float*)d_in[10];
    const float* fcW  = (const float*)d_in[11];
    const float* fcb  = (const float*)d_in[12];
    float* out = (float*)d_out;

    const int N = in_sizes[2];       // 100000
    const int E = in_sizes[1] / 2;   // 1600000
    const int G = out_size / 2;      // 256
    const int tot = E + N;
    const int NB = (N + NPB - 1) / NPB;   // 391 buckets

    // ws layout (~46 MiB): pairs ALIASES bufO (disjoint lifetimes:
    // pairs die at build_csr; bufO first written by aggregate layer 1).
    float* ws     = (float*)d_ws;
    float* bufO   = ws;                                  // N*64 fp32  25.6 MB
    unsigned int* pairs  = (unsigned int*)bufO;          // alias      7.2 MB
    float* als    = bufO + (size_t)N * 64;               // N          0.4 MB
    float* ald    = als + N;                             // N          0.4 MB
    int*   rowptr = (int*)(ald + N);                     // N+1        0.4 MB
    int*   srcs   = rowptr + N + 1;                      // tot        6.8 MB
    int*   bcur   = srcs + tot;                          // NB
    unsigned short* bufH16 = (unsigned short*)(bcur + NB);  // N*64   12.8 MB

    dim3 b256(256);
    int gPart = (E + EPB - 1) / EPB;
    int gGemm = (N + 63) / 64;
    int gAgg  = (N + 31) / 32;

    // ---- memset cursors + fused {partition || gemm1} + CSR fill ------------
    hipMemsetAsync(bcur, 0, (size_t)NB * sizeof(int), stream);
    part_gemm<<<gPart + gGemm, b256, 0, stream>>>(ei, E, NB, bcur, pairs, gPart,
                                                  x, W1, as1, ad1,
                                                  bufH16, als, ald, N);
    build_csr<<<NB, b256, 0, stream>>>(pairs, bcur, N, NB, rowptr, srcs);

    // ---- layer 1 aggregate ----
    gat_aggregate<<<gAgg, b256, 0, stream>>>(rowptr, srcs, als, ald, bufH16, bufO, N);

    // ---- layer 2 (input = leaky(bufO + b1, 0.01)) ----
    node_gemm<64><<<gGemm, b256, 0, stream>>>(bufO, W2, as2, ad2, b1, 0.01f,
                                              bufH16, als, ald, N);
    gat_aggregate<<<gAgg, b256, 0, stream>>>(rowptr, srcs, als, ald, bufH16, bufO, N);

    // ---- fused pool + fc ----
    pool_fc<<<G, b256, 0, stream>>>(bufO, b2, batch, fcW, fcb, out, N);
}

// Round 19
// 285.540 us; speedup vs baseline: 1.1223x; 1.0078x over previous
//
#include <hip/hip_runtime.h>
#include <hip/hip_bf16.h>
#include <math.h>

// ---------------------------------------------------------------------------
// GAT: 2x GATConv(heads=1) + global mean pool + FC(64->2)
// R30 = R29 (best, 287.8us) with the fusion RE-PAIRED:
//   R29 paired partition(9us) || gemm1(15us), leaving build_csr(~14us) to
//   run alone at 1.5 blocks/CU. R30: partition runs solo, then
//   [build_csr || gemm1] fused -- similar-duration pair, csr's idle CUs
//   filled by gemm blocks. csr LDS phase-union'd ({c,s2}|{hist,hcur}|
//   {deg,cur,S} sequential-with-barriers) -> 45->39KB, so the union with
//   gemm's 38KB keeps 4 blocks/CU. CSR blocks first (long-pole starts t=0).
//   Aggregate / node_gemm<64> / pool_fc BYTE-IDENTICAL to R29.
// ---------------------------------------------------------------------------

#define NPB 256          // nodes per bucket
#define EPB 4096         // edges per partition block (256 thr x 16)
#define PSTRIDE 4608     // slots per bucket (lambda=4092, +8 sigma)
#define XPAD 68          // xs leading-dim pad: 8-way banks, 16B-aligned rows

__device__ __forceinline__ unsigned int f2bf(float v) {
    unsigned int b = __float_as_uint(v);
    b += 0x7FFFu + ((b >> 16) & 1u);   // round-to-nearest-even
    return b >> 16;
}

// inclusive scan of one value per thread across 256 threads: wave64 shuffle
// scan + cross-wave combine via 4-entry LDS. Exactly 2 __syncthreads().
__device__ __forceinline__ int scanIncl256(int v, int t, int* wsum) {
    int lane = t & 63, wv = t >> 6;
#pragma unroll
    for (int o = 1; o < 64; o <<= 1) {
        int u = __shfl_up(v, o);
        if (lane >= o) v += u;
    }
    if (lane == 63) wsum[wv] = v;
    __syncthreads();
    int base = 0;
#pragma unroll
    for (int i = 0; i < 3; i++) base += (i < wv) ? wsum[i] : 0;
    __syncthreads();                     // guards wsum reuse by next call
    return v + base;
}

// --- partition edges into fixed-stride dst-buckets (packed uint32) ----------
// LDS-staged coalesced flush (R26). int4 edge loads (R24). Shuffle scan (R28).
__global__ __launch_bounds__(256) void partition(const int* __restrict__ ei,
                                                 int E, int NB,
                                                 int* __restrict__ bcur,
                                                 unsigned int* __restrict__ pairs) {
    __shared__ int h[512];                 // per-bucket counts
    __shared__ int ls[512];                // exclusive local starts
    __shared__ int lcur[512];              // scatter cursors
    __shared__ int hb[512];                // global bases
    __shared__ int s2[256];
    __shared__ int wsum[4];
    __shared__ unsigned int Qp[EPB];       // 16 KB staged vals
    __shared__ unsigned short Bq[EPB];     // 8 KB bucket ids
    int t = threadIdx.x;
    for (int i = t; i < 512; i += 256) h[i] = 0;
    __syncthreads();
    int i0 = blockIdx.x * EPB;
    unsigned int val[16];
    int bk[16];
    const int4* s4p = (const int4*)(ei);
    const int4* d4p = (const int4*)(ei + E);
#pragma unroll
    for (int k = 0; k < 4; k++) {
        int vbase = (i0 >> 2) + k * 256 + t;   // int4 index
        int i = vbase << 2;
        if (i < E) {                           // E%4==0 -> whole int4 valid
            int4 s4 = s4p[vbase];
            int4 d4 = d4p[vbase];
            int ss[4] = {s4.x, s4.y, s4.z, s4.w};
            int dd[4] = {d4.x, d4.y, d4.z, d4.w};
#pragma unroll
            for (int j = 0; j < 4; j++) {
                int e = k * 4 + j;
                bk[e] = dd[j] >> 8;
                val[e] = (unsigned)ss[j] | ((unsigned)(dd[j] & 255) << 24);
                atomicAdd(&h[bk[e]], 1);
            }
        } else {
#pragma unroll
            for (int j = 0; j < 4; j++) bk[k * 4 + j] = -1;
        }
    }
    __syncthreads();
    // exclusive scan of h[0..511] via pairwise shuffle scan (2 barriers)
    int p0 = h[2 * t], p1 = h[2 * t + 1];
    int incl = scanIncl256(p0 + p1, t, wsum);
    s2[t] = incl;
    int ex = incl - p0 - p1;
    ls[2 * t] = ex;           ls[2 * t + 1] = ex + p0;
    lcur[2 * t] = ex;         lcur[2 * t + 1] = ex + p0;
    __syncthreads();
    // global bases (one atomic per non-empty bucket)
    for (int b = t; b < NB; b += 256)
        hb[b] = h[b] ? atomicAdd(&bcur[b], h[b]) : 0;
    __syncthreads();
    // LDS scatter by local rank
#pragma unroll
    for (int e = 0; e < 16; e++) {
        if (bk[e] < 0) continue;
        int pos = atomicAdd(&lcur[bk[e]], 1);
        Qp[pos] = val[e];
        Bq[pos] = (unsigned short)bk[e];
    }
    __syncthreads();
    // linear flush: consecutive j -> same bucket -> adjacent global slots
    int total = s2[255];
    for (int j = t; j < total; j += 256) {
        int bkj = Bq[j];
        int gp = hb[bkj] + (j - ls[bkj]);
        if (gp < PSTRIDE)                  // overflow guard (stat. impossible)
            pairs[(size_t)bkj * PSTRIDE + gp] = Qp[j];
    }
}

// --- fused build_csr + gemm1 shared-memory layout ---------------------------
struct CsrP1 { int c[512]; int s2[256]; };                    // 3 KB (scan)
struct CsrP2 { int hist[256]; int hcur[256]; };               // 2 KB (sort)
struct CsrP3 { int deg[NPB]; int cur[NPB]; int S[NPB + PSTRIDE]; }; // 21.5 KB
struct CsrSh {
    unsigned int Q[PSTRIDE];              // 18.4 KB, live across phases
    union { CsrP1 p1; CsrP2 p2; CsrP3 p3; } u;   // 21.5 KB phase union
    int wsum[4];
    int sbase, stot;
};                                        // ~39.0 KB
struct GemmSh72 { float Ws[72 * 64]; float xs[72][XPAD]; };   // ~37.1 KB
union CsrGemmSh { CsrSh c; GemmSh72 g; }; // ~39.0 KB -> 4 blocks/CU

// --- fused kernel: blocks [0,NB) build CSR; rest do gemm layer 1 ------------
__global__ __launch_bounds__(256) void csr_gemm(const unsigned int* __restrict__ pairs,
                                                const int* __restrict__ bcur,
                                                int n, int NB,
                                                int* __restrict__ rowptr,
                                                int* __restrict__ srcs,
                                                const float* __restrict__ x,
                                                const float* __restrict__ W,
                                                const float* __restrict__ a_src,
                                                const float* __restrict__ a_dst,
                                                unsigned short* __restrict__ h16,
                                                float* __restrict__ al_s,
                                                float* __restrict__ al_d) {
    __shared__ CsrGemmSh sh;
    int t = threadIdx.x;
    if ((int)blockIdx.x < NB) {
        // ================= build_csr body (R28, phase-union LDS) ===========
        int b = blockIdx.x;
        // ---- phase 1: global bucket-count scan (c, s2) ----
        int c0 = (2 * t < NB) ? min(bcur[2 * t], PSTRIDE) : 0;
        int c1 = (2 * t + 1 < NB) ? min(bcur[2 * t + 1], PSTRIDE) : 0;
        sh.c.u.p1.c[2 * t] = c0; sh.c.u.p1.c[2 * t + 1] = c1;
        __syncthreads();
        int incl = scanIncl256(c0 + c1, t, sh.c.wsum);
        sh.c.u.p1.s2[t] = incl;
        __syncthreads();
        if (t == 0) {
            int p = b >> 1;
            int ex = sh.c.u.p1.s2[p] - (sh.c.u.p1.c[2 * p] + sh.c.u.p1.c[2 * p + 1]);
            sh.c.sbase = ex + ((b & 1) ? sh.c.u.p1.c[b & ~1] : 0);
            sh.c.stot = sh.c.u.p1.s2[255];
        }
        __syncthreads();
        int d0 = b << 8;
        int nb = min(NPB, n - d0);
        int cnt_b = sh.c.u.p1.c[b];       // read BEFORE phase 2 overwrites
        int csr0 = sh.c.sbase + d0;       // pairs before + self-loops before
        const unsigned int* pb = pairs + (size_t)b * PSTRIDE;
        __syncthreads();                  // all c[] reads done -> reuse union

        // ---- phase 2: counting sort by src>>9 into Q (hist, hcur) ----
        sh.c.u.p2.hist[t] = 0;
        __syncthreads();
        for (int j = t; j < cnt_b; j += 256)
            atomicAdd(&sh.c.u.p2.hist[(pb[j] & 0xFFFFFFu) >> 9], 1);  // key<=195
        __syncthreads();
        int hv = sh.c.u.p2.hist[t];
        int hincl = scanIncl256(hv, t, sh.c.wsum);
        sh.c.u.p2.hcur[t] = hincl - hv;   // exclusive base -> cursor
        __syncthreads();
        for (int j = t; j < cnt_b; j += 256) {
            unsigned int p = pb[j];
            int pos = atomicAdd(&sh.c.u.p2.hcur[(p & 0xFFFFFFu) >> 9], 1);
            sh.c.Q[pos] = p;
        }
        __syncthreads();                  // sort done -> reuse union

        // ---- phase 3: degree count / scan / fill into S (deg, cur, S) ----
        sh.c.u.p3.deg[t] = (t < nb) ? 1 : 0;   // self-loop
        __syncthreads();
        for (int j = t; j < cnt_b; j += 256)
            atomicAdd(&sh.c.u.p3.deg[sh.c.Q[j] >> 24], 1);
        __syncthreads();
        int v = sh.c.u.p3.deg[t];
        int dincl = scanIncl256(v, t, sh.c.wsum);
        int excl = dincl - v;
        if (t < nb) {
            rowptr[d0 + t] = csr0 + excl;
            sh.c.u.p3.S[excl] = d0 + t;   // self-loop at slot 0
            sh.c.u.p3.cur[t] = excl + 1;
        }
        __syncthreads();
        // j-round order over sorted Q -> node lists fill ~ascending in src
        for (int j = t; j < cnt_b; j += 256) {
            unsigned int p = sh.c.Q[j];
            int off = atomicAdd(&sh.c.u.p3.cur[p >> 24], 1);
            sh.c.u.p3.S[off] = (int)(p & 0x00FFFFFFu);
        }
        __syncthreads();
        // coalesced flush of the block's whole srcs segment
        int seg = nb + cnt_b;
        for (int j = t; j < seg; j += 256)
            srcs[csr0 + j] = sh.c.u.p3.S[j];
        if (b == 0 && t == 0) rowptr[n] = n + sh.c.stot;
    } else {
        // ================= gemm layer-1 body (R21, IN_DIM=72) ==============
        constexpr int IN_DIM = 72;
        float* Ws = sh.g.Ws;
        int nbase = ((int)blockIdx.x - NB) * 64;

        for (int idx = t; idx < IN_DIM * 16; idx += 256)
            ((float4*)Ws)[idx] = ((const float4*)W)[idx];
        const float* xb = x + (size_t)nbase * IN_DIM;
        int lim = min(64, n - nbase) * IN_DIM;           // in floats
        constexpr int NV = (64 * IN_DIM) / 4;            // float4 elements
        for (int idx = t; idx < NV; idx += 256) {
            int f0 = idx * 4;
            float4 v = make_float4(0.0f, 0.0f, 0.0f, 0.0f);
            if (f0 < lim) v = ((const float4*)xb)[idx];  // coalesced 16B/lane
            int node = f0 / IN_DIM;
            int k = f0 - node * IN_DIM;
            sh.g.xs[k + 0][node] = v.x;
            sh.g.xs[k + 1][node] = v.y;
            sh.g.xs[k + 2][node] = v.z;
            sh.g.xs[k + 3][node] = v.w;
        }
        __syncthreads();

        int cg = t & 15;    // col group: cols 4cg..4cg+3
        int ng = t >> 4;    // node group: nodes 4ng..4ng+3
        float acc[4][4] = {};
#pragma unroll 8
        for (int k = 0; k < IN_DIM; k++) {
            float4 xv = *(const float4*)&sh.g.xs[k][ng * 4];
            float4 wv = *(const float4*)&Ws[k * 64 + cg * 4];
            float xa[4] = {xv.x, xv.y, xv.z, xv.w};
            float wa[4] = {wv.x, wv.y, wv.z, wv.w};
#pragma unroll
            for (int i = 0; i < 4; i++)
#pragma unroll
                for (int j = 0; j < 4; j++)
                    acc[i][j] += xa[i] * wa[j];
        }

        float4 as4 = *(const float4*)(a_src + cg * 4);
        float4 ad4 = *(const float4*)(a_dst + cg * 4);
#pragma unroll
        for (int i = 0; i < 4; i++) {
            int node = nbase + ng * 4 + i;
            if (node < n) {
                uint2 p;
                p.x = f2bf(acc[i][0]) | (f2bf(acc[i][1]) << 16);
                p.y = f2bf(acc[i][2]) | (f2bf(acc[i][3]) << 16);
                *(uint2*)(h16 + (size_t)node * 64 + cg * 4) = p;
            }
            float vs = acc[i][0] * as4.x + acc[i][1] * as4.y +
                       acc[i][2] * as4.z + acc[i][3] * as4.w;
            float vd = acc[i][0] * ad4.x + acc[i][1] * ad4.y +
                       acc[i][2] * ad4.z + acc[i][3] * ad4.w;
#pragma unroll
            for (int o = 8; o; o >>= 1) {
                vs += __shfl_xor(vs, o);
                vd += __shfl_xor(vd, o);
            }
            if (cg == 0 && node < n) { al_s[node] = vs; al_d[node] = vd; }
        }
    }
}

// --- tiled node GEMM (layer 2): 64 nodes x 64 cols, float4 staging ----------
template <int IN_DIM>
__global__ __launch_bounds__(256) void node_gemm(const float* __restrict__ x,
                                                 const float* __restrict__ W,
                                                 const float* __restrict__ a_src,
                                                 const float* __restrict__ a_dst,
                                                 const float* __restrict__ bias_in,
                                                 float slope_in,
                                                 unsigned short* __restrict__ h16,
                                                 float* __restrict__ al_s,
                                                 float* __restrict__ al_d,
                                                 int n) {
    __shared__ float Ws[IN_DIM * 64];
    __shared__ float xs[IN_DIM][XPAD];
    int t = threadIdx.x;
    int nbase = blockIdx.x * 64;

    for (int idx = t; idx < IN_DIM * 16; idx += 256)
        ((float4*)Ws)[idx] = ((const float4*)W)[idx];
    const float* xb = x + (size_t)nbase * IN_DIM;
    int lim = min(64, n - nbase) * IN_DIM;           // in floats
    constexpr int NV = (64 * IN_DIM) / 4;            // float4 elements
    for (int idx = t; idx < NV; idx += 256) {
        int f0 = idx * 4;
        float4 v = make_float4(0.0f, 0.0f, 0.0f, 0.0f);
        if (f0 < lim) v = ((const float4*)xb)[idx];  // coalesced 16B/lane
        int node = f0 / IN_DIM;
        int k = f0 - node * IN_DIM;
        if (bias_in) {
            v.x += bias_in[k + 0];
            v.y += bias_in[k + 1];
            v.z += bias_in[k + 2];
            v.w += bias_in[k + 3];
            v.x = (v.x >= 0.0f) ? v.x : slope_in * v.x;
            v.y = (v.y >= 0.0f) ? v.y : slope_in * v.y;
            v.z = (v.z >= 0.0f) ? v.z : slope_in * v.z;
            v.w = (v.w >= 0.0f) ? v.w : slope_in * v.w;
        }
        xs[k + 0][node] = v.x;
        xs[k + 1][node] = v.y;
        xs[k + 2][node] = v.z;
        xs[k + 3][node] = v.w;
    }
    __syncthreads();

    int cg = t & 15;    // col group: cols 4cg..4cg+3
    int ng = t >> 4;    // node group: nodes 4ng..4ng+3
    float acc[4][4] = {};
#pragma unroll 8
    for (int k = 0; k < IN_DIM; k++) {
        float4 xv = *(const float4*)&xs[k][ng * 4];
        float4 wv = *(const float4*)&Ws[k * 64 + cg * 4];
        float xa[4] = {xv.x, xv.y, xv.z, xv.w};
        float wa[4] = {wv.x, wv.y, wv.z, wv.w};
#pragma unroll
        for (int i = 0; i < 4; i++)
#pragma unroll
            for (int j = 0; j < 4; j++)
                acc[i][j] += xa[i] * wa[j];
    }

    float4 as4 = *(const float4*)(a_src + cg * 4);
    float4 ad4 = *(const float4*)(a_dst + cg * 4);
#pragma unroll
    for (int i = 0; i < 4; i++) {
        int node = nbase + ng * 4 + i;
        if (node < n) {
            uint2 p;
            p.x = f2bf(acc[i][0]) | (f2bf(acc[i][1]) << 16);
            p.y = f2bf(acc[i][2]) | (f2bf(acc[i][3]) << 16);
            *(uint2*)(h16 + (size_t)node * 64 + cg * 4) = p;
        }
        float vs = acc[i][0] * as4.x + acc[i][1] * as4.y +
                   acc[i][2] * as4.z + acc[i][3] * as4.w;
        float vd = acc[i][0] * ad4.x + acc[i][1] * ad4.y +
                   acc[i][2] * ad4.z + acc[i][3] * ad4.w;
#pragma unroll
        for (int o = 8; o; o >>= 1) {
            vs += __shfl_xor(vs, o);
            vd += __shfl_xor(vd, o);
        }
        if (cg == 0 && node < n) { al_s[node] = vs; al_d[node] = vd; }
    }
}

// --- single-pass aggregate (R17 proven body, BYTE-IDENTICAL): ---------------
// 8 lanes/node, depth-4 prefetch. 53.4us / 32 VGPR / no spill.
// out[node] = (sum_j exp(e_j)*h[src_j]) / (sum_j exp(e_j) + 1e-16)
__device__ __forceinline__ void bf8_fma(float* acc, uint4 q, float w) {
    acc[0] += w * __uint_as_float(q.x << 16);
    acc[1] += w * __uint_as_float(q.x & 0xFFFF0000u);
    acc[2] += w * __uint_as_float(q.y << 16);
    acc[3] += w * __uint_as_float(q.y & 0xFFFF0000u);
    acc[4] += w * __uint_as_float(q.z << 16);
    acc[5] += w * __uint_as_float(q.z & 0xFFFF0000u);
    acc[6] += w * __uint_as_float(q.w << 16);
    acc[7] += w * __uint_as_float(q.w & 0xFFFF0000u);
}

__global__ __launch_bounds__(256) void gat_aggregate(const int* __restrict__ rowptr,
                                                     const int* __restrict__ srcs,
                                                     const float* __restrict__ als,
                                                     const float* __restrict__ ald,
                                                     const unsigned short* __restrict__ h16,
                                                     float* __restrict__ hout,
                                                     int n) {
    int t = threadIdx.x;
    int sub = t >> 3, lane = t & 7;       // 32 nodes/block, 8 lanes/node
    int node = blockIdx.x * 32 + sub;
    if (node >= n) return;
    int beg = rowptr[node], end = rowptr[node + 1];
    float aldv = ald[node];
    const unsigned short* hb = h16 + lane * 8;

    float acc[8] = {};
    float sm = 0.0f;
    int j = beg;
    if (j + 4 <= end) {
        int s0 = srcs[j], s1 = srcs[j + 1], s2 = srcs[j + 2], s3 = srcs[j + 3];
        for (; j + 8 <= end; j += 4) {
            // prefetch next quad's indices: breaks srcs->gather serial chain
            int n0 = srcs[j + 4], n1 = srcs[j + 5];
            int n2 = srcs[j + 6], n3 = srcs[j + 7];
            float e0 = als[s0] + aldv, e1 = als[s1] + aldv;
            float e2 = als[s2] + aldv, e3 = als[s3] + aldv;
            uint4 q0 = *(const uint4*)(hb + (size_t)s0 * 64);
            uint4 q1 = *(const uint4*)(hb + (size_t)s1 * 64);
            uint4 q2 = *(const uint4*)(hb + (size_t)s2 * 64);
            uint4 q3 = *(const uint4*)(hb + (size_t)s3 * 64);
            e0 = (e0 >= 0.0f) ? e0 : 0.2f * e0;
            e1 = (e1 >= 0.0f) ? e1 : 0.2f * e1;
            e2 = (e2 >= 0.0f) ? e2 : 0.2f * e2;
            e3 = (e3 >= 0.0f) ? e3 : 0.2f * e3;
            float w0 = __expf(e0), w1 = __expf(e1);
            float w2 = __expf(e2), w3 = __expf(e3);
            sm += (w0 + w1) + (w2 + w3);
            bf8_fma(acc, q0, w0);
            bf8_fma(acc, q1, w1);
            bf8_fma(acc, q2, w2);
            bf8_fma(acc, q3, w3);
            s0 = n0; s1 = n1; s2 = n2; s3 = n3;
        }
        // final full quad (s0..s3 already loaded)
        {
            float e0 = als[s0] + aldv, e1 = als[s1] + aldv;
            float e2 = als[s2] + aldv, e3 = als[s3] + aldv;
            uint4 q0 = *(const uint4*)(hb + (size_t)s0 * 64);
            uint4 q1 = *(const uint4*)(hb + (size_t)s1 * 64);
            uint4 q2 = *(const uint4*)(hb + (size_t)s2 * 64);
            uint4 q3 = *(const uint4*)(hb + (size_t)s3 * 64);
            e0 = (e0 >= 0.0f) ? e0 : 0.2f * e0;
            e1 = (e1 >= 0.0f) ? e1 : 0.2f * e1;
            e2 = (e2 >= 0.0f) ? e2 : 0.2f * e2;
            e3 = (e3 >= 0.0f) ? e3 : 0.2f * e3;
            float w0 = __expf(e0), w1 = __expf(e1);
            float w2 = __expf(e2), w3 = __expf(e3);
            sm += (w0 + w1) + (w2 + w3);
            bf8_fma(acc, q0, w0);
            bf8_fma(acc, q1, w1);
            bf8_fma(acc, q2, w2);
            bf8_fma(acc, q3, w3);
            j += 4;
        }
    }
    for (; j < end; j++) {
        int s = srcs[j];
        float e = als[s] + aldv;
        e = (e >= 0.0f) ? e : 0.2f * e;
        float w = __expf(e);
        uint4 q = *(const uint4*)(hb + (size_t)s * 64);
        sm += w;
        bf8_fma(acc, q, w);
    }

    float inv = 1.0f / (sm + 1e-16f);
    float4 o0 = make_float4(acc[0] * inv, acc[1] * inv, acc[2] * inv, acc[3] * inv);
    float4 o1 = make_float4(acc[4] * inv, acc[5] * inv, acc[6] * inv, acc[7] * inv);
    float* op = hout + (size_t)node * 64 + lane * 8;
    *(float4*)op = o0;
    *(float4*)(op + 4) = o1;
}

// --- fused pool + FC: one block per graph, float4 hout reads ----------------
__global__ __launch_bounds__(256) void pool_fc(const float* __restrict__ hout,
                                               const float* __restrict__ b2,
                                               const int* __restrict__ batch,
                                               const float* __restrict__ fcW,
                                               const float* __restrict__ fcb,
                                               float* __restrict__ out, int n) {
    int g = blockIdx.x;
    int t = threadIdx.x;
    __shared__ int sLo, sHi;
    __shared__ float red[16][64];
    if (t == 0) {
        int lo = 0, hi = n;
        while (lo < hi) { int m = (lo + hi) >> 1; if (batch[m] < g) lo = m + 1; else hi = m; }
        sLo = lo;
    } else if (t == 64) {
        int lo = 0, hi = n;
        while (lo < hi) { int m = (lo + hi) >> 1; if (batch[m] < g + 1) lo = m + 1; else hi = m; }
        sHi = lo;
    }
    __syncthreads();
    int lo = sLo, hi = sHi;
    int q = t & 15;     // float4 index within 64-float row
    int r = t >> 4;     // node offset (stride 16)
    float4 a4 = make_float4(0.0f, 0.0f, 0.0f, 0.0f);
    for (int node = lo + r; node < hi; node += 16) {
        float4 v = *(const float4*)(hout + (size_t)node * 64 + q * 4);
        a4.x += v.x; a4.y += v.y; a4.z += v.z; a4.w += v.w;
    }
    *(float4*)&red[r][q * 4] = a4;
    __syncthreads();
    if (t < 64) {
        float c = (float)(hi - lo);
        float s = 0.0f;
#pragma unroll
        for (int i = 0; i < 16; i++) s += red[i][t];
        s += c * b2[t];
        float cd = (c > 1.0f) ? c : 1.0f;
        float p = s / cd;
        float s0 = p * fcW[t * 2 + 0];
        float s1 = p * fcW[t * 2 + 1];
#pragma unroll
        for (int o = 32; o; o >>= 1) {
            s0 += __shfl_xor(s0, o);
            s1 += __shfl_xor(s1, o);
        }
        if (t == 0) {
            out[g * 2 + 0] = s0 + fcb[0];
            out[g * 2 + 1] = s1 + fcb[1];
        }
    }
}

extern "C" void kernel_launch(void* const* d_in, const int* in_sizes, int n_in,
                              void* d_out, int out_size, void* d_ws, size_t ws_size,
                              hipStream_t stream) {
    const float* x    = (const float*)d_in[0];
    const int*   ei   = (const int*)d_in[1];
    const int*   batch= (const int*)d_in[2];
    const float* W1   = (const float*)d_in[3];
    const float* as1  = (const float*)d_in[4];
    const float* ad1  = (const float*)d_in[5];
    const float* b1   = (const float*)d_in[6];
    const float* W2   = (const float*)d_in[7];
    const float* as2  = (const float*)d_in[8];
    const float* ad2  = (const float*)d_in[9];
    const float* b2   = (const float*)d_in[10];
    const float* fcW  = (const float*)d_in[11];
    const float* fcb  = (const float*)d_in[12];
    float* out = (float*)d_out;

    const int N = in_sizes[2];       // 100000
    const int E = in_sizes[1] / 2;   // 1600000
    const int G = out_size / 2;      // 256
    const int tot = E + N;
    const int NB = (N + NPB - 1) / NPB;   // 391 buckets

    // ws layout (~46 MiB): pairs ALIASES bufO (disjoint lifetimes:
    // pairs die at csr_gemm; bufO first written by aggregate layer 1).
    float* ws     = (float*)d_ws;
    float* bufO   = ws;                                  // N*64 fp32  25.6 MB
    unsigned int* pairs  = (unsigned int*)bufO;          // alias      7.2 MB
    float* als    = bufO + (size_t)N * 64;               // N          0.4 MB
    float* ald    = als + N;                             // N          0.4 MB
    int*   rowptr = (int*)(ald + N);                     // N+1        0.4 MB
    int*   srcs   = rowptr + N + 1;                      // tot        6.8 MB
    int*   bcur   = srcs + tot;                          // NB
    unsigned short* bufH16 = (unsigned short*)(bcur + NB);  // N*64   12.8 MB

    dim3 b256(256);
    int gPart = (E + EPB - 1) / EPB;
    int gGemm = (N + 63) / 64;
    int gAgg  = (N + 31) / 32;

    // ---- memset + partition + fused {build_csr || gemm1} -------------------
    hipMemsetAsync(bcur, 0, (size_t)NB * sizeof(int), stream);
    partition<<<gPart, b256, 0, stream>>>(ei, E, NB, bcur, pairs);
    csr_gemm<<<NB + gGemm, b256, 0, stream>>>(pairs, bcur, N, NB, rowptr, srcs,
                                              x, W1, as1, ad1,
                                              bufH16, als, ald);

    // ---- layer 1 aggregate ----
    gat_aggregate<<<gAgg, b256, 0, stream>>>(rowptr, srcs, als, ald, bufH16, bufO, N);

    // ---- layer 2 (input = leaky(bufO + b1, 0.01)) ----
    node_gemm<64><<<gGemm, b256, 0, stream>>>(bufO, W2, as2, ad2, b1, 0.01f,
                                              bufH16, als, ald, N);
    gat_aggregate<<<gAgg, b256, 0, stream>>>(rowptr, srcs, als, ald, bufH16, bufO, N);

    // ---- fused pool + fc ----
    pool_fc<<<G, b256, 0, stream>>>(bufO, b2, batch, fcW, fcb, out, N);
}